// Round 12
// baseline (469.491 us; speedup 1.0000x reference)
//
#include <hip/hip_runtime.h>

// ---------- types & helpers ----------
typedef __attribute__((ext_vector_type(8))) short short8;
typedef __attribute__((ext_vector_type(4))) float f32x4;

#define MFMA16 __builtin_amdgcn_mfma_f32_16x16x32_bf16

#define GLOAD16(gp, lp) __builtin_amdgcn_global_load_lds(                      \
    (const __attribute__((address_space(1))) void*)(gp),                       \
    (__attribute__((address_space(3))) void*)(lp), 16, 0, 0)

__device__ __forceinline__ unsigned short f2bf(float f) {
  unsigned int u = __float_as_uint(f);
  unsigned int r = u + 0x7fffu + ((u >> 16) & 1u);
  return (unsigned short)(r >> 16);
}
__device__ __forceinline__ float bf2f(unsigned short h) {
  return __uint_as_float(((unsigned int)h) << 16);
}

// ---------- cast fp32 -> bf16 (vector4) ----------
__global__ __launch_bounds__(256) void cast_x_kernel(
    const float* __restrict__ in, unsigned short* __restrict__ out, int n4) {
  int i = blockIdx.x * 256 + threadIdx.x;
  if (i >= n4) return;
  float4 v = reinterpret_cast<const float4*>(in)[i];
  ushort4 o;
  o.x = f2bf(v.x); o.y = f2bf(v.y); o.z = f2bf(v.z); o.w = f2bf(v.w);
  reinterpret_cast<ushort4*>(out)[i] = o;
}

// ---------- transpose + cast fp32 -> bf16 : out[C][R] = in[R][C] ----------
__global__ __launch_bounds__(256) void tcast_f32_kernel(
    const float* __restrict__ in, unsigned short* __restrict__ out, int R, int C) {
  __shared__ float t[64][65];
  int c0 = blockIdx.x * 64, r0 = blockIdx.y * 64;
  int tx = threadIdx.x, ty = threadIdx.y;  // (64,4)
#pragma unroll
  for (int i = 0; i < 16; ++i)
    t[ty + 4 * i][tx] = in[(size_t)(r0 + ty + 4 * i) * C + c0 + tx];
  __syncthreads();
#pragma unroll
  for (int i = 0; i < 16; ++i)
    out[(size_t)(c0 + ty + 4 * i) * R + r0 + tx] = f2bf(t[tx][ty + 4 * i]);
}

// ---------- batched: transpose+cast the four 1024x1024 weight matrices ----------
__global__ __launch_bounds__(256) void tcast4_kernel(
    const float* __restrict__ i0, const float* __restrict__ i1,
    const float* __restrict__ i2, const float* __restrict__ i3,
    unsigned short* __restrict__ o0, unsigned short* __restrict__ o1,
    unsigned short* __restrict__ o2, unsigned short* __restrict__ o3) {
  const float* in = i0; unsigned short* out = o0;
  if (blockIdx.z == 1) { in = i1; out = o1; }
  else if (blockIdx.z == 2) { in = i2; out = o2; }
  else if (blockIdx.z == 3) { in = i3; out = o3; }
  __shared__ float t[64][65];
  int c0 = blockIdx.x * 64, r0 = blockIdx.y * 64;
  int tx = threadIdx.x, ty = threadIdx.y;  // (64,4)
#pragma unroll
  for (int i = 0; i < 16; ++i)
    t[ty + 4 * i][tx] = in[(size_t)(r0 + ty + 4 * i) * 1024 + c0 + tx];
  __syncthreads();
#pragma unroll
  for (int i = 0; i < 16; ++i)
    out[(size_t)(c0 + ty + 4 * i) * 1024 + r0 + tx] = f2bf(t[tx][ty + 4 * i]);
}

// ---------- big GEMM  C[M,1024] = A[M,1024] @ W (W stored [N][K]) ----------
// B-DIRECT variant: W fragments are loaded straight from global (W is 2MB ->
// L2/L3-resident); only A goes through LDS, double-buffered 2 x 8KB with a
// depth-1 prefetch (stage t+1 issued before the MFMAs of t; B loads issued
// FIRST so the compiler's auto-wait for B is vmcnt(2), keeping the A-prefetch
// in flight; the single __syncthreads per iter retires it).
// OUTF==1: fp32 out, grid (128,8,1).
// OUTF==3: grid (3072,1,1), z-interleaved decode (3 z-variants of a tile are
//   8 IDs apart -> same XCD, A panel L2-reused). z<2: bf16 out; z==2: bf16
//   transposed out to vT[b*1024+n][tok] via 4x 32-col passes through the
//   static 16KB LDS.
template <int OUTF>
__global__ __launch_bounds__(256) void gemm_bt_kernel(
    const unsigned short* __restrict__ A,
    const unsigned short* W0, const unsigned short* W1, const unsigned short* W2,
    const float* b0, const float* b1, const float* b2,
    void* o0, void* o1, void* o2) {
  constexpr int KD = 1024, ND = 1024;
  int m0, n0, z;
  if constexpr (OUTF == 3) {
    int id = blockIdx.x;
    int g = id / 24, slot = id - g * 24;
    z = slot >> 3;
    int t = g * 8 + (slot & 7);
    m0 = (t & 127) * 128;
    n0 = (t >> 7) * 128;
  } else {
    m0 = blockIdx.x * 128;
    n0 = blockIdx.y * 128;
    z = 0;
  }
  const unsigned short* W = W0; const float* bias = b0; void* op = o0;
  if (z == 1) { W = W1; bias = b1; op = o1; }
  else if (z == 2) { W = W2; bias = b2; op = o2; }

  __shared__ unsigned short lsA[2][4096];  // 2 x 8KB A tiles (128 rows x 32 k)
  int tid = threadIdx.x;
  int w = tid >> 6, lane = tid & 63;
  int lo = lane & 15, hi = lane >> 4;
  int wm = (w >> 1) * 64, wn = (w & 1) * 64;

  // A staging: wave w covers rows [w*32, w*32+32) as 2 lines of 16 rows
  int srow0 = (w * 2 + 0) * 16 + (lane >> 2);
  int srow1 = (w * 2 + 1) * 16 + (lane >> 2);
  int scol = (lane & 3) * 8;
  const unsigned short* gA0 = A + (size_t)(m0 + srow0) * KD + scol;
  const unsigned short* gA1 = A + (size_t)(m0 + srow1) * KD + scol;

  // B fragment base pointers (direct global)
  const unsigned short* gBf[4];
#pragma unroll
  for (int fn = 0; fn < 4; ++fn)
    gBf[fn] = W + (size_t)(n0 + wn + fn * 16 + lo) * KD + hi * 8;

  f32x4 acc[4][4];
#pragma unroll
  for (int fm = 0; fm < 4; ++fm)
#pragma unroll
    for (int fn = 0; fn < 4; ++fn) acc[fm][fn] = (f32x4){0.f, 0.f, 0.f, 0.f};

  // prologue: stage A tile 0 -> buf 0
  GLOAD16(gA0, &lsA[0][(w * 2 + 0) * 512]);
  GLOAD16(gA1, &lsA[0][(w * 2 + 1) * 512]);
  __syncthreads();

#pragma unroll 2
  for (int kt = 0; kt < KD; kt += 32) {
    int buf = (kt >> 5) & 1;
    // 1. B fragment loads (oldest in vmcnt FIFO)
    short8 bfr[4];
#pragma unroll
    for (int fn = 0; fn < 4; ++fn)
      bfr[fn] = *reinterpret_cast<const short8*>(gBf[fn] + kt);
    __builtin_amdgcn_sched_barrier(0);
    // 2. A prefetch for next tile -> other buffer (stays in flight over MFMAs)
    if (kt + 32 < KD) {
      GLOAD16(gA0 + kt + 32, &lsA[buf ^ 1][(w * 2 + 0) * 512]);
      GLOAD16(gA1 + kt + 32, &lsA[buf ^ 1][(w * 2 + 1) * 512]);
    }
    __builtin_amdgcn_sched_barrier(0);
    // 3. A fragments from LDS + MFMA (compiler inserts vmcnt(2) for B use)
    short8 af[4];
#pragma unroll
    for (int fm = 0; fm < 4; ++fm)
      af[fm] = *reinterpret_cast<const short8*>(
          &lsA[buf][(wm + fm * 16 + lo) * 32 + hi * 8]);
#pragma unroll
    for (int fm = 0; fm < 4; ++fm)
#pragma unroll
      for (int fn = 0; fn < 4; ++fn)
        acc[fm][fn] = MFMA16(af[fm], bfr[fn], acc[fm][fn], 0, 0, 0);
    __builtin_amdgcn_sched_barrier(0);
    __syncthreads();  // drains the A prefetch; next iter reads buf^1
  }

  bool vpath = (OUTF == 3) && (z == 2);
  if (!vpath) {
#pragma unroll
    for (int fn = 0; fn < 4; ++fn) {
      int coll = wn + fn * 16 + lo;
      float bv = bias[n0 + coll];
#pragma unroll
      for (int fm = 0; fm < 4; ++fm) {
#pragma unroll
        for (int j = 0; j < 4; ++j) {
          int rowl = wm + fm * 16 + hi * 4 + j;
          float v = acc[fm][fn][j] + bv;
          if constexpr (OUTF == 1)
            reinterpret_cast<float*>(op)[(size_t)(m0 + rowl) * ND + n0 + coll] = v;
          else
            reinterpret_cast<unsigned short*>(op)[(size_t)(m0 + rowl) * ND + n0 + coll] =
                f2bf(v);
        }
      }
    }
  } else {
    // vT transpose epilogue: 4 passes of 32 cols through static LDS (8.5KB/pass)
    unsigned short* tt = &lsA[0][0];  // 16KB flat, K-loop done
    int b = m0 >> 12, tok0 = m0 & 4095;
    int c2 = tid >> 3, q = (tid & 7) * 16;
#pragma unroll
    for (int p = 0; p < 4; ++p) {
      __syncthreads();
      if (wn == (p >> 1) * 64) {
        int fb = (p & 1) * 2;
#pragma unroll
        for (int fi = 0; fi < 2; ++fi) {
          int fn = fb + fi;
          int cp = fi * 16 + lo;  // col within this 32-col pass
          float bv = bias[n0 + p * 32 + cp];
#pragma unroll
          for (int fm = 0; fm < 4; ++fm)
#pragma unroll
            for (int j = 0; j < 4; ++j)
              tt[cp * 136 + wm + fm * 16 + hi * 4 + j] = f2bf(acc[fm][fn][j] + bv);
        }
      }
      __syncthreads();
      unsigned short* dst = reinterpret_cast<unsigned short*>(op) +
                            (size_t)(b * 1024 + n0 + p * 32 + c2) * 4096 + tok0 + q;
      *reinterpret_cast<short8*>(dst) =
          *reinterpret_cast<const short8*>(&tt[c2 * 136 + q]);
      *reinterpret_cast<short8*>(dst + 8) =
          *reinterpret_cast<const short8*>(&tt[c2 * 136 + q + 8]);
    }
  }
}

// ---------- fused featmap(k) + kv + ksum (split over N, S=8) ----------
// K: [16384][1024] bf16, PT: [256][64] bf16, VT: [(b*16+h)*64+d][4096] bf16
// kvp: [8][64 bh][256 f][64 d] fp32 parts, ksp: [8][64][256] fp32 parts
__global__ __launch_bounds__(256) void kv_fused_kernel(
    const unsigned short* __restrict__ K, const unsigned short* __restrict__ PT,
    const unsigned short* __restrict__ VT,
    float* __restrict__ kvp, float* __restrict__ ksp) {
  __shared__ unsigned short kp[256 * 40];  // [f][n] transposed k' tile, stride 40
  int s = blockIdx.x, bh = blockIdx.y, b = bh >> 4, h = bh & 15;
  int tid = threadIdx.x, w = tid >> 6, lane = tid & 63;
  int lo = lane & 15, hi = lane >> 4;
  int f0w = w * 64;

  short8 pb[4][2];
#pragma unroll
  for (int fn = 0; fn < 4; ++fn) {
    int f = f0w + fn * 16 + lo;
    pb[fn][0] = *reinterpret_cast<const short8*>(PT + (size_t)f * 64 + hi * 8);
    pb[fn][1] = *reinterpret_cast<const short8*>(PT + (size_t)f * 64 + 32 + hi * 8);
  }
  const unsigned short* vbase[4];
#pragma unroll
  for (int fn = 0; fn < 4; ++fn)
    vbase[fn] = VT + (size_t)(bh * 64 + fn * 16 + lo) * 4096;

  f32x4 acck[4][4];
#pragma unroll
  for (int fm = 0; fm < 4; ++fm)
#pragma unroll
    for (int fn = 0; fn < 4; ++fn) acck[fm][fn] = (f32x4){0.f, 0.f, 0.f, 0.f};
  float ks[4] = {0.f, 0.f, 0.f, 0.f};

  for (int c = 0; c < 16; ++c) {
    int n0 = s * 512 + c * 32;
    const unsigned short* Ab = K + (size_t)(b * 4096 + n0) * 1024 + h * 64;
    short8 af[2][2], b2[4];
#pragma unroll
    for (int fm = 0; fm < 2; ++fm)
#pragma unroll
      for (int kt = 0; kt < 2; ++kt)
        af[fm][kt] = *reinterpret_cast<const short8*>(
            Ab + (size_t)(fm * 16 + lo) * 1024 + kt * 32 + hi * 8);
#pragma unroll
    for (int fn = 0; fn < 4; ++fn)
      b2[fn] = *reinterpret_cast<const short8*>(vbase[fn] + n0 + hi * 8);

    float dp[2] = {0.f, 0.f};
#pragma unroll
    for (int fm = 0; fm < 2; ++fm)
#pragma unroll
      for (int kt = 0; kt < 2; ++kt)
#pragma unroll
        for (int j = 0; j < 8; ++j) {
          float qv = bf2f((unsigned short)af[fm][kt][j]);
          dp[fm] += qv * qv;
        }
#pragma unroll
    for (int fm = 0; fm < 2; ++fm) {
      dp[fm] += __shfl_xor(dp[fm], 16);
      dp[fm] += __shfl_xor(dp[fm], 32);
    }
    f32x4 accf[2][4];
#pragma unroll
    for (int fm = 0; fm < 2; ++fm)
#pragma unroll
      for (int fn = 0; fn < 4; ++fn) accf[fm][fn] = (f32x4){0.f, 0.f, 0.f, 0.f};
#pragma unroll
    for (int fn = 0; fn < 4; ++fn) {
      accf[0][fn] = MFMA16(af[0][0], pb[fn][0], accf[0][fn], 0, 0, 0);
      accf[0][fn] = MFMA16(af[0][1], pb[fn][1], accf[0][fn], 0, 0, 0);
      accf[1][fn] = MFMA16(af[1][0], pb[fn][0], accf[1][fn], 0, 0, 0);
      accf[1][fn] = MFMA16(af[1][1], pb[fn][1], accf[1][fn], 0, 0, 0);
    }
#pragma unroll
    for (int fm = 0; fm < 2; ++fm)
#pragma unroll
      for (int fn = 0; fn < 4; ++fn) {
        ushort4 pk;
#pragma unroll
        for (int j = 0; j < 4; ++j) {
          float dg = __shfl(dp[fm], hi * 4 + j);
          float v = 0.125f *
                    (__expf(0.35355339059327373f * accf[fm][fn][j] - 0.0625f * dg) + 1e-6f);
          ks[fn] += v;
          ((unsigned short*)&pk)[j] = f2bf(v);
        }
        *reinterpret_cast<ushort4*>(&kp[(f0w + fn * 16 + lo) * 40 + fm * 16 + hi * 4]) = pk;
      }
    short8 a2[4];
#pragma unroll
    for (int fm = 0; fm < 4; ++fm)
      a2[fm] = *reinterpret_cast<const short8*>(&kp[(f0w + fm * 16 + lo) * 40 + hi * 8]);
#pragma unroll
    for (int fm = 0; fm < 4; ++fm)
#pragma unroll
      for (int fn = 0; fn < 4; ++fn)
        acck[fm][fn] = MFMA16(a2[fm], b2[fn], acck[fm][fn], 0, 0, 0);
  }
#pragma unroll
  for (int fn = 0; fn < 4; ++fn) {
    float v = ks[fn];
    v += __shfl_xor(v, 16);
    v += __shfl_xor(v, 32);
    if (hi == 0)
      ksp[(size_t)(s * 64 + bh) * 256 + f0w + fn * 16 + lo] = v;
  }
#pragma unroll
  for (int fm = 0; fm < 4; ++fm)
#pragma unroll
    for (int fn = 0; fn < 4; ++fn)
#pragma unroll
      for (int j = 0; j < 4; ++j)
        kvp[((size_t)(s * 64 + bh) * 256 + f0w + fm * 16 + hi * 4 + j) * 64 + fn * 16 + lo] =
            acck[fm][fn][j];
}

// ---------- reduce parts -> kvT bf16 [bh][64 d][256 f], ksum fp32 [bh][256] ----------
__global__ __launch_bounds__(256) void kvred_kernel(
    const float* __restrict__ kvp, const float* __restrict__ ksp,
    unsigned short* __restrict__ kvT, float* __restrict__ ksum) {
  __shared__ float t[64][65];
  int bh = blockIdx.x, g = blockIdx.y, tid = threadIdx.x;
  int fbase = g * 64;
  int fo = tid >> 2, dq = (tid & 3) * 16;
  float sum[16];
#pragma unroll
  for (int i = 0; i < 16; ++i) sum[i] = 0.f;
#pragma unroll
  for (int s = 0; s < 8; ++s) {
    const float* base = kvp + ((size_t)(s * 64 + bh) * 256 + fbase + fo) * 64 + dq;
#pragma unroll
    for (int i = 0; i < 16; ++i) sum[i] += base[i];
  }
#pragma unroll
  for (int i = 0; i < 16; ++i) t[fo][dq + i] = sum[i];
  __syncthreads();
  int d = tid >> 2, fq = (tid & 3) * 16;
  unsigned short wv[16];
#pragma unroll
  for (int i = 0; i < 16; ++i) wv[i] = f2bf(t[fq + i][d]);
  unsigned short* dst = kvT + (size_t)(bh * 64 + d) * 256 + fbase + fq;
  *reinterpret_cast<short8*>(dst) = *reinterpret_cast<const short8*>(&wv[0]);
  *reinterpret_cast<short8*>(dst + 8) = *reinterpret_cast<const short8*>(&wv[8]);
  if (g == 0) {
    float tsum = 0.f;
#pragma unroll
    for (int s = 0; s < 8; ++s) tsum += ksp[(size_t)(s * 64 + bh) * 256 + tid];
    ksum[bh * 256 + tid] = tsum;
  }
}

// ---------- fused featmap(q) + qkv + norm (f split into two 128-halves) ----------
__global__ __launch_bounds__(256) void qkv_fused_kernel(
    const unsigned short* __restrict__ Q, const unsigned short* __restrict__ PT,
    const unsigned short* __restrict__ KVT, const float* __restrict__ KSUM,
    unsigned short* __restrict__ Y) {
  __shared__ unsigned short qp[128 * 128];  // XOR-swizzled q' half-tile (32KB)
  int bh = blockIdx.y, b = bh >> 4, h = bh & 15;
  int t0 = blockIdx.x * 128;
  int tid = threadIdx.x, w = tid >> 6, lane = tid & 63;
  int lo = lane & 15, hi = lane >> 4;
  int r0 = w * 32;
  const unsigned short* Ab = Q + (size_t)(b * 4096 + t0 + r0) * 1024 + h * 64;

  float ksr[16];
#pragma unroll
  for (int fn = 0; fn < 16; ++fn) ksr[fn] = KSUM[bh * 256 + fn * 16 + lo];

  short8 af[2][2];
  float dp[2] = {0.f, 0.f};
#pragma unroll
  for (int fm = 0; fm < 2; ++fm)
#pragma unroll
    for (int kt = 0; kt < 2; ++kt) {
      af[fm][kt] = *reinterpret_cast<const short8*>(
          Ab + (size_t)(fm * 16 + lo) * 1024 + kt * 32 + hi * 8);
#pragma unroll
      for (int j = 0; j < 8; ++j) {
        float qv = bf2f((unsigned short)af[fm][kt][j]);
        dp[fm] += qv * qv;
      }
    }
#pragma unroll
  for (int fm = 0; fm < 2; ++fm) {
    dp[fm] += __shfl_xor(dp[fm], 16);
    dp[fm] += __shfl_xor(dp[fm], 32);
  }

  float np[2][4] = {{0.f, 0.f, 0.f, 0.f}, {0.f, 0.f, 0.f, 0.f}};
  f32x4 acco[2][4];
#pragma unroll
  for (int fm = 0; fm < 2; ++fm)
#pragma unroll
    for (int fn = 0; fn < 4; ++fn) acco[fm][fn] = (f32x4){0.f, 0.f, 0.f, 0.f};

#pragma unroll
  for (int hf = 0; hf < 2; ++hf) {
    f32x4 accf[2][8];
#pragma unroll
    for (int fm = 0; fm < 2; ++fm)
#pragma unroll
      for (int fn = 0; fn < 8; ++fn) accf[fm][fn] = (f32x4){0.f, 0.f, 0.f, 0.f};
#pragma unroll
    for (int fn = 0; fn < 8; ++fn) {
      int f = hf * 128 + fn * 16 + lo;
      short8 pb0 = *reinterpret_cast<const short8*>(PT + (size_t)f * 64 + hi * 8);
      short8 pb1 = *reinterpret_cast<const short8*>(PT + (size_t)f * 64 + 32 + hi * 8);
      accf[0][fn] = MFMA16(af[0][0], pb0, accf[0][fn], 0, 0, 0);
      accf[0][fn] = MFMA16(af[0][1], pb1, accf[0][fn], 0, 0, 0);
      accf[1][fn] = MFMA16(af[1][0], pb0, accf[1][fn], 0, 0, 0);
      accf[1][fn] = MFMA16(af[1][1], pb1, accf[1][fn], 0, 0, 0);
    }
#pragma unroll
    for (int fm = 0; fm < 2; ++fm)
#pragma unroll
      for (int fn = 0; fn < 8; ++fn)
#pragma unroll
        for (int j = 0; j < 4; ++j) {
          float dg = __shfl(dp[fm], hi * 4 + j);
          float v = 0.125f *
                    (__expf(0.35355339059327373f * accf[fm][fn][j] - 0.0625f * dg) + 1e-6f);
          np[fm][j] += v * ksr[hf * 8 + fn];
          int row = r0 + fm * 16 + hi * 4 + j;
          int fl = fn * 16 + lo;
          int byt = (row * 256 + fl * 2) ^ ((row & 7) << 4);
          *reinterpret_cast<unsigned short*>(reinterpret_cast<char*>(qp) + byt) = f2bf(v);
        }
#pragma unroll
    for (int kt2 = 0; kt2 < 4; ++kt2) {
      short8 a2[2], b2[4];
#pragma unroll
      for (int fm = 0; fm < 2; ++fm) {
        int row = r0 + fm * 16 + lo;
        int byt = (row * 256 + kt2 * 64 + hi * 16) ^ ((row & 7) << 4);
        a2[fm] = *reinterpret_cast<const short8*>(reinterpret_cast<char*>(qp) + byt);
      }
#pragma unroll
      for (int fn = 0; fn < 4; ++fn)
        b2[fn] = *reinterpret_cast<const short8*>(
            KVT + (size_t)(bh * 64 + fn * 16 + lo) * 256 + hf * 128 + kt2 * 32 + hi * 8);
#pragma unroll
      for (int fm = 0; fm < 2; ++fm)
#pragma unroll
        for (int fn = 0; fn < 4; ++fn)
          acco[fm][fn] = MFMA16(a2[fm], b2[fn], acco[fm][fn], 0, 0, 0);
    }
  }
#pragma unroll
  for (int fm = 0; fm < 2; ++fm)
#pragma unroll
    for (int j = 0; j < 4; ++j) {
      np[fm][j] += __shfl_xor(np[fm][j], 1);
      np[fm][j] += __shfl_xor(np[fm][j], 2);
      np[fm][j] += __shfl_xor(np[fm][j], 4);
      np[fm][j] += __shfl_xor(np[fm][j], 8);
    }
#pragma unroll
  for (int fm = 0; fm < 2; ++fm)
#pragma unroll
    for (int j = 0; j < 4; ++j) {
      float nv = np[fm][j] + 1e-6f;
      int row = b * 4096 + t0 + r0 + fm * 16 + hi * 4 + j;
#pragma unroll
      for (int fn = 0; fn < 4; ++fn)
        Y[(size_t)row * 1024 + h * 64 + fn * 16 + lo] = f2bf(acco[fm][fn][j] / nv);
    }
}

// ---------- host ----------
extern "C" void kernel_launch(void* const* d_in, const int* in_sizes, int n_in,
                              void* d_out, int out_size, void* d_ws, size_t ws_size,
                              hipStream_t stream) {
  (void)in_sizes; (void)n_in; (void)out_size; (void)ws_size;
  const float* x    = (const float*)d_in[0];
  const float* Wq   = (const float*)d_in[2];
  const float* bq   = (const float*)d_in[3];
  const float* Wk   = (const float*)d_in[4];
  const float* bk   = (const float*)d_in[5];
  const float* Wv   = (const float*)d_in[6];
  const float* bv   = (const float*)d_in[7];
  const float* Wo   = (const float*)d_in[8];
  const float* bo   = (const float*)d_in[9];
  const float* proj = (const float*)d_in[10];
  float* out = (float*)d_out;

  constexpr size_t SZ_XB = (size_t)16384 * 1024 * 2;  // 32 MiB
  constexpr size_t SZ_W  = (size_t)1024 * 1024 * 2;   // 2 MiB
  constexpr size_t SZ_PT = (size_t)256 * 64 * 2;      // 32 KiB

  char* p = (char*)d_ws;
  size_t off = 0;
  char* a_xb  = p + off; off += SZ_XB;
  char* a_WqT = p + off; off += SZ_W;
  char* a_WkT = p + off; off += SZ_W;
  char* a_WvT = p + off; off += SZ_W;
  char* a_WoT = p + off; off += SZ_W;
  char* a_pT  = p + off; off += SZ_PT;
  char* a_qb  = p + off; off += SZ_XB;
  char* a_kb  = p + off; off += SZ_XB;
  char* a_ksp  = p + off; off += (size_t)8 * 64 * 256 * 4;       // 512 KiB
  char* a_kvT  = p + off; off += (size_t)64 * 64 * 256 * 2;      // 2 MiB
  char* a_ksum = p + off; off += (size_t)64 * 256 * 4;           // 64 KiB

  // Aliases (stream-order verified):
  // kvp parts (8 x 4 MiB = 32 MiB) alias xb — xb dead after the QKV GEMM.
  char* a_kvp = a_xb;
  // vT lives in d_out lower half; d_out fully overwritten by the final GEMM.
  char* a_vT = (char*)d_out;
  // y aliases kb (K data dead after kv_fused).
  char* a_y = a_kb;

  dim3 tb(64, 4);

  cast_x_kernel<<<16384, 256, 0, stream>>>(x, (unsigned short*)a_xb, 16384 * 1024 / 4);
  tcast4_kernel<<<dim3(16, 16, 4), tb, 0, stream>>>(
      Wq, Wk, Wv, Wo,
      (unsigned short*)a_WqT, (unsigned short*)a_WkT,
      (unsigned short*)a_WvT, (unsigned short*)a_WoT);
  tcast_f32_kernel<<<dim3(4, 1), tb, 0, stream>>>(proj, (unsigned short*)a_pT, 64, 256);

  // q, k, v in one z-interleaved launch; z==2 writes vT via LDS-transpose.
  gemm_bt_kernel<3><<<3072, 256, 0, stream>>>(
      (unsigned short*)a_xb,
      (unsigned short*)a_WqT, (unsigned short*)a_WkT, (unsigned short*)a_WvT,
      bq, bk, bv, a_qb, a_kb, a_vT);

  kv_fused_kernel<<<dim3(8, 64), 256, 0, stream>>>(
      (unsigned short*)a_kb, (unsigned short*)a_pT, (unsigned short*)a_vT,
      (float*)a_kvp, (float*)a_ksp);
  kvred_kernel<<<dim3(64, 4), 256, 0, stream>>>(
      (float*)a_kvp, (float*)a_ksp, (unsigned short*)a_kvT, (float*)a_ksum);

  qkv_fused_kernel<<<dim3(32, 64), 256, 0, stream>>>(
      (unsigned short*)a_qb, (unsigned short*)a_pT, (unsigned short*)a_kvT,
      (float*)a_ksum, (unsigned short*)a_y);

  gemm_bt_kernel<1><<<dim3(128, 8, 1), 256, 0, stream>>>(
      (unsigned short*)a_y,
      (unsigned short*)a_WoT, nullptr, nullptr,
      bo, nullptr, nullptr, out, nullptr, nullptr);
}

// Round 13
// 341.201 us; speedup vs baseline: 1.3760x; 1.3760x over previous
//
#include <hip/hip_runtime.h>

// ---------- types & helpers ----------
typedef __attribute__((ext_vector_type(8))) short short8;
typedef __attribute__((ext_vector_type(4))) float f32x4;

#define MFMA16 __builtin_amdgcn_mfma_f32_16x16x32_bf16

#define GLOAD16(gp, lp) __builtin_amdgcn_global_load_lds(                      \
    (const __attribute__((address_space(1))) void*)(gp),                       \
    (__attribute__((address_space(3))) void*)(lp), 16, 0, 0)

__device__ __forceinline__ unsigned short f2bf(float f) {
  unsigned int u = __float_as_uint(f);
  unsigned int r = u + 0x7fffu + ((u >> 16) & 1u);
  return (unsigned short)(r >> 16);
}
__device__ __forceinline__ float bf2f(unsigned short h) {
  return __uint_as_float(((unsigned int)h) << 16);
}

// ---------- cast fp32 -> bf16 (vector4) ----------
__global__ __launch_bounds__(256) void cast_x_kernel(
    const float* __restrict__ in, unsigned short* __restrict__ out, int n4) {
  int i = blockIdx.x * 256 + threadIdx.x;
  if (i >= n4) return;
  float4 v = reinterpret_cast<const float4*>(in)[i];
  ushort4 o;
  o.x = f2bf(v.x); o.y = f2bf(v.y); o.z = f2bf(v.z); o.w = f2bf(v.w);
  reinterpret_cast<ushort4*>(out)[i] = o;
}

// ---------- transpose + cast fp32 -> bf16 : out[C][R] = in[R][C] ----------
__global__ __launch_bounds__(256) void tcast_f32_kernel(
    const float* __restrict__ in, unsigned short* __restrict__ out, int R, int C) {
  __shared__ float t[64][65];
  int c0 = blockIdx.x * 64, r0 = blockIdx.y * 64;
  int tx = threadIdx.x, ty = threadIdx.y;  // (64,4)
#pragma unroll
  for (int i = 0; i < 16; ++i)
    t[ty + 4 * i][tx] = in[(size_t)(r0 + ty + 4 * i) * C + c0 + tx];
  __syncthreads();
#pragma unroll
  for (int i = 0; i < 16; ++i)
    out[(size_t)(c0 + ty + 4 * i) * R + r0 + tx] = f2bf(t[tx][ty + 4 * i]);
}

// ---------- batched: transpose+cast the four 1024x1024 weight matrices ----------
__global__ __launch_bounds__(256) void tcast4_kernel(
    const float* __restrict__ i0, const float* __restrict__ i1,
    const float* __restrict__ i2, const float* __restrict__ i3,
    unsigned short* __restrict__ o0, unsigned short* __restrict__ o1,
    unsigned short* __restrict__ o2, unsigned short* __restrict__ o3) {
  const float* in = i0; unsigned short* out = o0;
  if (blockIdx.z == 1) { in = i1; out = o1; }
  else if (blockIdx.z == 2) { in = i2; out = o2; }
  else if (blockIdx.z == 3) { in = i3; out = o3; }
  __shared__ float t[64][65];
  int c0 = blockIdx.x * 64, r0 = blockIdx.y * 64;
  int tx = threadIdx.x, ty = threadIdx.y;  // (64,4)
#pragma unroll
  for (int i = 0; i < 16; ++i)
    t[ty + 4 * i][tx] = in[(size_t)(r0 + ty + 4 * i) * 1024 + c0 + tx];
  __syncthreads();
#pragma unroll
  for (int i = 0; i < 16; ++i)
    out[(size_t)(c0 + ty + 4 * i) * 1024 + r0 + tx] = f2bf(t[tx][ty + 4 * i]);
}

// ---------- big GEMM  C[M,1024] = A[M,1024] @ W (W stored [N][K]) ----------
// R8/R11 core (BK=32, VGPR~80, 3 blocks/CU). This is the measured local
// optimum for this shape: 7 structural probes (256^2 deep pipelines x4,
// BK=64 swizzled, B-direct) all landed 152-238us vs this kernel's 155us.
// Binding constraint: m97-structure barrier drain at ~30% MfmaUtil; not
// fetch-bound (z-interleave moved FETCH 98->91MB, duration unchanged).
// OUTF==1: fp32 out, grid (128,8,1).
// OUTF==3: grid (3072,1,1) with z-interleaved XCD-aware decode:
//   g=id/24, slot=id%24, z=slot>>3, t=g*8+(slot&7), x=t&127, y=t>>7.
//   z<2: bf16 normal out; z==2: bf16 transposed out to vT[b*1024+n][tok]
//   via dynamic-LDS (34816B) per-batch transpose epilogue.
template <int OUTF>
__global__ __launch_bounds__(256) void gemm_bt_kernel(
    const unsigned short* __restrict__ A,
    const unsigned short* W0, const unsigned short* W1, const unsigned short* W2,
    const float* b0, const float* b1, const float* b2,
    void* o0, void* o1, void* o2) {
  constexpr int KD = 1024, ND = 1024;
  int m0, n0, z;
  if constexpr (OUTF == 3) {
    int id = blockIdx.x;
    int g = id / 24, slot = id - g * 24;
    z = slot >> 3;
    int t = g * 8 + (slot & 7);
    m0 = (t & 127) * 128;
    n0 = (t >> 7) * 128;
  } else {
    m0 = blockIdx.x * 128;
    n0 = blockIdx.y * 128;
    z = 0;
  }
  const unsigned short* W = W0; const float* bias = b0; void* op = o0;
  if (z == 1) { W = W1; bias = b1; op = o1; }
  else if (z == 2) { W = W2; bias = b2; op = o2; }

  __shared__ unsigned short lsA[128 * 32];
  __shared__ unsigned short lsB[128 * 32];
  extern __shared__ unsigned short tt[];  // allocated only for OUTF==3 launches
  int tid = threadIdx.x;
  int w = tid >> 6, lane = tid & 63;
  int lo = lane & 15, hi = lane >> 4;
  int wm = (w >> 1) * 64, wn = (w & 1) * 64;

  int srow0 = (w * 2 + 0) * 16 + (lane >> 2);
  int srow1 = (w * 2 + 1) * 16 + (lane >> 2);
  int scol = (lane & 3) * 8;
  const unsigned short* gA0 = A + (size_t)(m0 + srow0) * KD + scol;
  const unsigned short* gA1 = A + (size_t)(m0 + srow1) * KD + scol;
  const unsigned short* gB0 = W + (size_t)(n0 + srow0) * KD + scol;
  const unsigned short* gB1 = W + (size_t)(n0 + srow1) * KD + scol;
  unsigned short* lA0 = &lsA[(w * 2 + 0) * 512];
  unsigned short* lA1 = &lsA[(w * 2 + 1) * 512];
  unsigned short* lB0 = &lsB[(w * 2 + 0) * 512];
  unsigned short* lB1 = &lsB[(w * 2 + 1) * 512];

  f32x4 acc[4][4];
#pragma unroll
  for (int fm = 0; fm < 4; ++fm)
#pragma unroll
    for (int fn = 0; fn < 4; ++fn) acc[fm][fn] = (f32x4){0.f, 0.f, 0.f, 0.f};

  for (int kt = 0; kt < KD; kt += 32) {
    GLOAD16(gA0 + kt, lA0);
    GLOAD16(gA1 + kt, lA1);
    GLOAD16(gB0 + kt, lB0);
    GLOAD16(gB1 + kt, lB1);
    __syncthreads();
    short8 af[4], bfr[4];
#pragma unroll
    for (int fm = 0; fm < 4; ++fm)
      af[fm] = *reinterpret_cast<const short8*>(
          &lsA[(wm + fm * 16 + lo) * 32 + hi * 8]);
#pragma unroll
    for (int fn = 0; fn < 4; ++fn)
      bfr[fn] = *reinterpret_cast<const short8*>(
          &lsB[(wn + fn * 16 + lo) * 32 + hi * 8]);
#pragma unroll
    for (int fm = 0; fm < 4; ++fm)
#pragma unroll
      for (int fn = 0; fn < 4; ++fn)
        acc[fm][fn] = MFMA16(af[fm], bfr[fn], acc[fm][fn], 0, 0, 0);
    __syncthreads();
  }

  bool vpath = (OUTF == 3) && (z == 2);
#pragma unroll
  for (int fn = 0; fn < 4; ++fn) {
    int coll = wn + fn * 16 + lo;
    float bv = bias[n0 + coll];
#pragma unroll
    for (int fm = 0; fm < 4; ++fm) {
#pragma unroll
      for (int j = 0; j < 4; ++j) {
        int rowl = wm + fm * 16 + hi * 4 + j;
        float v = acc[fm][fn][j] + bv;
        if constexpr (OUTF == 1) {
          reinterpret_cast<float*>(op)[(size_t)(m0 + rowl) * ND + n0 + coll] = v;
        } else {
          if (vpath)
            tt[coll * 136 + rowl] = f2bf(v);
          else
            reinterpret_cast<unsigned short*>(op)[(size_t)(m0 + rowl) * ND + n0 + coll] =
                f2bf(v);
        }
      }
    }
  }
  if constexpr (OUTF == 3) {
    if (vpath) {
      __syncthreads();
      int b = m0 >> 12, tok0 = m0 & 4095;
      int c = tid >> 1, half = (tid & 1) * 64;
      unsigned short* dst = reinterpret_cast<unsigned short*>(op) +
                            (size_t)(b * 1024 + n0 + c) * 4096 + tok0 + half;
#pragma unroll
      for (int i = 0; i < 8; ++i) {
        short8 vv = *reinterpret_cast<const short8*>(&tt[c * 136 + half + i * 8]);
        *reinterpret_cast<short8*>(dst + i * 8) = vv;
      }
    }
  }
}

// ---------- fused featmap(k) + kv + ksum (split over N, S=8) ----------
// K: [16384][1024] bf16, PT: [256][64] bf16, VT: [(b*16+h)*64+d][4096] bf16
// kvp: [8][64 bh][256 f][64 d] fp32 parts, ksp: [8][64][256] fp32 parts
__global__ __launch_bounds__(256) void kv_fused_kernel(
    const unsigned short* __restrict__ K, const unsigned short* __restrict__ PT,
    const unsigned short* __restrict__ VT,
    float* __restrict__ kvp, float* __restrict__ ksp) {
  __shared__ unsigned short kp[256 * 40];  // [f][n] transposed k' tile, stride 40
  int s = blockIdx.x, bh = blockIdx.y, b = bh >> 4, h = bh & 15;
  int tid = threadIdx.x, w = tid >> 6, lane = tid & 63;
  int lo = lane & 15, hi = lane >> 4;
  int f0w = w * 64;

  short8 pb[4][2];
#pragma unroll
  for (int fn = 0; fn < 4; ++fn) {
    int f = f0w + fn * 16 + lo;
    pb[fn][0] = *reinterpret_cast<const short8*>(PT + (size_t)f * 64 + hi * 8);
    pb[fn][1] = *reinterpret_cast<const short8*>(PT + (size_t)f * 64 + 32 + hi * 8);
  }
  const unsigned short* vbase[4];
#pragma unroll
  for (int fn = 0; fn < 4; ++fn)
    vbase[fn] = VT + (size_t)(bh * 64 + fn * 16 + lo) * 4096;

  f32x4 acck[4][4];
#pragma unroll
  for (int fm = 0; fm < 4; ++fm)
#pragma unroll
    for (int fn = 0; fn < 4; ++fn) acck[fm][fn] = (f32x4){0.f, 0.f, 0.f, 0.f};
  float ks[4] = {0.f, 0.f, 0.f, 0.f};

  for (int c = 0; c < 16; ++c) {
    int n0 = s * 512 + c * 32;
    const unsigned short* Ab = K + (size_t)(b * 4096 + n0) * 1024 + h * 64;
    // issue ALL global loads up front (K chunk + V chunk are independent)
    short8 af[2][2], b2[4];
#pragma unroll
    for (int fm = 0; fm < 2; ++fm)
#pragma unroll
      for (int kt = 0; kt < 2; ++kt)
        af[fm][kt] = *reinterpret_cast<const short8*>(
            Ab + (size_t)(fm * 16 + lo) * 1024 + kt * 32 + hi * 8);
#pragma unroll
    for (int fn = 0; fn < 4; ++fn)
      b2[fn] = *reinterpret_cast<const short8*>(vbase[fn] + n0 + hi * 8);

    float dp[2] = {0.f, 0.f};
#pragma unroll
    for (int fm = 0; fm < 2; ++fm)
#pragma unroll
      for (int kt = 0; kt < 2; ++kt)
#pragma unroll
        for (int j = 0; j < 8; ++j) {
          float qv = bf2f((unsigned short)af[fm][kt][j]);
          dp[fm] += qv * qv;
        }
#pragma unroll
    for (int fm = 0; fm < 2; ++fm) {
      dp[fm] += __shfl_xor(dp[fm], 16);
      dp[fm] += __shfl_xor(dp[fm], 32);
    }
    f32x4 accf[2][4];
#pragma unroll
    for (int fm = 0; fm < 2; ++fm)
#pragma unroll
      for (int fn = 0; fn < 4; ++fn) accf[fm][fn] = (f32x4){0.f, 0.f, 0.f, 0.f};
#pragma unroll
    for (int fn = 0; fn < 4; ++fn) {
      accf[0][fn] = MFMA16(af[0][0], pb[fn][0], accf[0][fn], 0, 0, 0);
      accf[0][fn] = MFMA16(af[0][1], pb[fn][1], accf[0][fn], 0, 0, 0);
      accf[1][fn] = MFMA16(af[1][0], pb[fn][0], accf[1][fn], 0, 0, 0);
      accf[1][fn] = MFMA16(af[1][1], pb[fn][1], accf[1][fn], 0, 0, 0);
    }
    // exp epilogue -> packed ushort4 LDS writes (wave-private stripe)
#pragma unroll
    for (int fm = 0; fm < 2; ++fm)
#pragma unroll
      for (int fn = 0; fn < 4; ++fn) {
        ushort4 pk;
#pragma unroll
        for (int j = 0; j < 4; ++j) {
          float dg = __shfl(dp[fm], hi * 4 + j);
          float v = 0.125f *
                    (__expf(0.35355339059327373f * accf[fm][fn][j] - 0.0625f * dg) + 1e-6f);
          ks[fn] += v;
          ((unsigned short*)&pk)[j] = f2bf(v);
        }
        *reinterpret_cast<ushort4*>(&kp[(f0w + fn * 16 + lo) * 40 + fm * 16 + hi * 4]) = pk;
      }
    // kv MFMA: this wave's 64 f-rows x 64 d, K=32 (this chunk)
    short8 a2[4];
#pragma unroll
    for (int fm = 0; fm < 4; ++fm)
      a2[fm] = *reinterpret_cast<const short8*>(&kp[(f0w + fm * 16 + lo) * 40 + hi * 8]);
#pragma unroll
    for (int fm = 0; fm < 4; ++fm)
#pragma unroll
      for (int fn = 0; fn < 4; ++fn)
        acck[fm][fn] = MFMA16(a2[fm], b2[fn], acck[fm][fn], 0, 0, 0);
  }
#pragma unroll
  for (int fn = 0; fn < 4; ++fn) {
    float v = ks[fn];
    v += __shfl_xor(v, 16);
    v += __shfl_xor(v, 32);
    if (hi == 0)
      ksp[(size_t)(s * 64 + bh) * 256 + f0w + fn * 16 + lo] = v;
  }
#pragma unroll
  for (int fm = 0; fm < 4; ++fm)
#pragma unroll
    for (int fn = 0; fn < 4; ++fn)
#pragma unroll
      for (int j = 0; j < 4; ++j)
        kvp[((size_t)(s * 64 + bh) * 256 + f0w + fm * 16 + hi * 4 + j) * 64 + fn * 16 + lo] =
            acck[fm][fn][j];
}

// ---------- reduce parts -> kvT bf16 [bh][64 d][256 f], ksum fp32 [bh][256] ----------
__global__ __launch_bounds__(256) void kvred_kernel(
    const float* __restrict__ kvp, const float* __restrict__ ksp,
    unsigned short* __restrict__ kvT, float* __restrict__ ksum) {
  __shared__ float t[64][65];
  int bh = blockIdx.x, g = blockIdx.y, tid = threadIdx.x;
  int fbase = g * 64;
  int fo = tid >> 2, dq = (tid & 3) * 16;
  float sum[16];
#pragma unroll
  for (int i = 0; i < 16; ++i) sum[i] = 0.f;
#pragma unroll
  for (int s = 0; s < 8; ++s) {
    const float* base = kvp + ((size_t)(s * 64 + bh) * 256 + fbase + fo) * 64 + dq;
#pragma unroll
    for (int i = 0; i < 16; ++i) sum[i] += base[i];
  }
#pragma unroll
  for (int i = 0; i < 16; ++i) t[fo][dq + i] = sum[i];
  __syncthreads();
  int d = tid >> 2, fq = (tid & 3) * 16;
  unsigned short wv[16];
#pragma unroll
  for (int i = 0; i < 16; ++i) wv[i] = f2bf(t[fq + i][d]);
  unsigned short* dst = kvT + (size_t)(bh * 64 + d) * 256 + fbase + fq;
  *reinterpret_cast<short8*>(dst) = *reinterpret_cast<const short8*>(&wv[0]);
  *reinterpret_cast<short8*>(dst + 8) = *reinterpret_cast<const short8*>(&wv[8]);
  if (g == 0) {
    float tsum = 0.f;
#pragma unroll
    for (int s = 0; s < 8; ++s) tsum += ksp[(size_t)(s * 64 + bh) * 256 + tid];
    ksum[bh * 256 + tid] = tsum;
  }
}

// ---------- fused featmap(q) + qkv + norm (f split into two 128-halves) ----------
__global__ __launch_bounds__(256) void qkv_fused_kernel(
    const unsigned short* __restrict__ Q, const unsigned short* __restrict__ PT,
    const unsigned short* __restrict__ KVT, const float* __restrict__ KSUM,
    unsigned short* __restrict__ Y) {
  __shared__ unsigned short qp[128 * 128];  // XOR-swizzled q' half-tile (32KB)
  int bh = blockIdx.y, b = bh >> 4, h = bh & 15;
  int t0 = blockIdx.x * 128;
  int tid = threadIdx.x, w = tid >> 6, lane = tid & 63;
  int lo = lane & 15, hi = lane >> 4;
  int r0 = w * 32;
  const unsigned short* Ab = Q + (size_t)(b * 4096 + t0 + r0) * 1024 + h * 64;

  float ksr[16];
#pragma unroll
  for (int fn = 0; fn < 16; ++fn) ksr[fn] = KSUM[bh * 256 + fn * 16 + lo];

  short8 af[2][2];
  float dp[2] = {0.f, 0.f};
#pragma unroll
  for (int fm = 0; fm < 2; ++fm)
#pragma unroll
    for (int kt = 0; kt < 2; ++kt) {
      af[fm][kt] = *reinterpret_cast<const short8*>(
          Ab + (size_t)(fm * 16 + lo) * 1024 + kt * 32 + hi * 8);
#pragma unroll
      for (int j = 0; j < 8; ++j) {
        float qv = bf2f((unsigned short)af[fm][kt][j]);
        dp[fm] += qv * qv;
      }
    }
#pragma unroll
  for (int fm = 0; fm < 2; ++fm) {
    dp[fm] += __shfl_xor(dp[fm], 16);
    dp[fm] += __shfl_xor(dp[fm], 32);
  }

  float np[2][4] = {{0.f, 0.f, 0.f, 0.f}, {0.f, 0.f, 0.f, 0.f}};
  f32x4 acco[2][4];
#pragma unroll
  for (int fm = 0; fm < 2; ++fm)
#pragma unroll
    for (int fn = 0; fn < 4; ++fn) acco[fm][fn] = (f32x4){0.f, 0.f, 0.f, 0.f};

#pragma unroll
  for (int hf = 0; hf < 2; ++hf) {
    f32x4 accf[2][8];
#pragma unroll
    for (int fm = 0; fm < 2; ++fm)
#pragma unroll
      for (int fn = 0; fn < 8; ++fn) accf[fm][fn] = (f32x4){0.f, 0.f, 0.f, 0.f};
#pragma unroll
    for (int fn = 0; fn < 8; ++fn) {
      int f = hf * 128 + fn * 16 + lo;
      short8 pb0 = *reinterpret_cast<const short8*>(PT + (size_t)f * 64 + hi * 8);
      short8 pb1 = *reinterpret_cast<const short8*>(PT + (size_t)f * 64 + 32 + hi * 8);
      accf[0][fn] = MFMA16(af[0][0], pb0, accf[0][fn], 0, 0, 0);
      accf[0][fn] = MFMA16(af[0][1], pb1, accf[0][fn], 0, 0, 0);
      accf[1][fn] = MFMA16(af[1][0], pb0, accf[1][fn], 0, 0, 0);
      accf[1][fn] = MFMA16(af[1][1], pb1, accf[1][fn], 0, 0, 0);
    }
#pragma unroll
    for (int fm = 0; fm < 2; ++fm)
#pragma unroll
      for (int fn = 0; fn < 8; ++fn)
#pragma unroll
        for (int j = 0; j < 4; ++j) {
          float dg = __shfl(dp[fm], hi * 4 + j);
          float v = 0.125f *
                    (__expf(0.35355339059327373f * accf[fm][fn][j] - 0.0625f * dg) + 1e-6f);
          np[fm][j] += v * ksr[hf * 8 + fn];
          int row = r0 + fm * 16 + hi * 4 + j;
          int fl = fn * 16 + lo;
          int byt = (row * 256 + fl * 2) ^ ((row & 7) << 4);
          *reinterpret_cast<unsigned short*>(reinterpret_cast<char*>(qp) + byt) = f2bf(v);
        }
#pragma unroll
    for (int kt2 = 0; kt2 < 4; ++kt2) {
      short8 a2[2], b2[4];
#pragma unroll
      for (int fm = 0; fm < 2; ++fm) {
        int row = r0 + fm * 16 + lo;
        int byt = (row * 256 + kt2 * 64 + hi * 16) ^ ((row & 7) << 4);
        a2[fm] = *reinterpret_cast<const short8*>(reinterpret_cast<char*>(qp) + byt);
      }
#pragma unroll
      for (int fn = 0; fn < 4; ++fn)
        b2[fn] = *reinterpret_cast<const short8*>(
            KVT + (size_t)(bh * 64 + fn * 16 + lo) * 256 + hf * 128 + kt2 * 32 + hi * 8);
#pragma unroll
      for (int fm = 0; fm < 2; ++fm)
#pragma unroll
        for (int fn = 0; fn < 4; ++fn)
          acco[fm][fn] = MFMA16(a2[fm], b2[fn], acco[fm][fn], 0, 0, 0);
    }
  }
#pragma unroll
  for (int fm = 0; fm < 2; ++fm)
#pragma unroll
    for (int j = 0; j < 4; ++j) {
      np[fm][j] += __shfl_xor(np[fm][j], 1);
      np[fm][j] += __shfl_xor(np[fm][j], 2);
      np[fm][j] += __shfl_xor(np[fm][j], 4);
      np[fm][j] += __shfl_xor(np[fm][j], 8);
    }
#pragma unroll
  for (int fm = 0; fm < 2; ++fm)
#pragma unroll
    for (int j = 0; j < 4; ++j) {
      float nv = np[fm][j] + 1e-6f;
      int row = b * 4096 + t0 + r0 + fm * 16 + hi * 4 + j;
#pragma unroll
      for (int fn = 0; fn < 4; ++fn)
        Y[(size_t)row * 1024 + h * 64 + fn * 16 + lo] = f2bf(acco[fm][fn][j] / nv);
    }
}

// ---------- host ----------
extern "C" void kernel_launch(void* const* d_in, const int* in_sizes, int n_in,
                              void* d_out, int out_size, void* d_ws, size_t ws_size,
                              hipStream_t stream) {
  (void)in_sizes; (void)n_in; (void)out_size; (void)ws_size;
  const float* x    = (const float*)d_in[0];
  const float* Wq   = (const float*)d_in[2];
  const float* bq   = (const float*)d_in[3];
  const float* Wk   = (const float*)d_in[4];
  const float* bk   = (const float*)d_in[5];
  const float* Wv   = (const float*)d_in[6];
  const float* bv   = (const float*)d_in[7];
  const float* Wo   = (const float*)d_in[8];
  const float* bo   = (const float*)d_in[9];
  const float* proj = (const float*)d_in[10];
  float* out = (float*)d_out;

  constexpr size_t SZ_XB = (size_t)16384 * 1024 * 2;  // 32 MiB
  constexpr size_t SZ_W  = (size_t)1024 * 1024 * 2;   // 2 MiB
  constexpr size_t SZ_PT = (size_t)256 * 64 * 2;      // 32 KiB

  char* p = (char*)d_ws;
  size_t off = 0;
  char* a_xb  = p + off; off += SZ_XB;
  char* a_WqT = p + off; off += SZ_W;
  char* a_WkT = p + off; off += SZ_W;
  char* a_WvT = p + off; off += SZ_W;
  char* a_WoT = p + off; off += SZ_W;
  char* a_pT  = p + off; off += SZ_PT;
  char* a_qb  = p + off; off += SZ_XB;
  char* a_kb  = p + off; off += SZ_XB;
  char* a_ksp  = p + off; off += (size_t)8 * 64 * 256 * 4;       // 512 KiB
  char* a_kvT  = p + off; off += (size_t)64 * 64 * 256 * 2;      // 2 MiB
  char* a_ksum = p + off; off += (size_t)64 * 256 * 4;           // 64 KiB

  // Aliases (stream-order verified):
  // kvp parts (8 x 4 MiB = 32 MiB) alias xb — xb dead after the QKV GEMM.
  char* a_kvp = a_xb;
  // vT lives in d_out lower half; d_out fully overwritten by the final GEMM.
  char* a_vT = (char*)d_out;
  // y aliases kb (K data dead after kv_fused).
  char* a_y = a_kb;

  dim3 tb(64, 4);

  cast_x_kernel<<<16384, 256, 0, stream>>>(x, (unsigned short*)a_xb, 16384 * 1024 / 4);
  tcast4_kernel<<<dim3(16, 16, 4), tb, 0, stream>>>(
      Wq, Wk, Wv, Wo,
      (unsigned short*)a_WqT, (unsigned short*)a_WkT,
      (unsigned short*)a_WvT, (unsigned short*)a_WoT);
  tcast_f32_kernel<<<dim3(4, 1), tb, 0, stream>>>(proj, (unsigned short*)a_pT, 64, 256);

  // q, k, v in one z-interleaved launch; z==2 writes vT via LDS-transpose.
  gemm_bt_kernel<3><<<3072, 256, 128 * 136 * 2, stream>>>(
      (unsigned short*)a_xb,
      (unsigned short*)a_WqT, (unsigned short*)a_WkT, (unsigned short*)a_WvT,
      bq, bk, bv, a_qb, a_kb, a_vT);

  kv_fused_kernel<<<dim3(8, 64), 256, 0, stream>>>(
      (unsigned short*)a_kb, (unsigned short*)a_pT, (unsigned short*)a_vT,
      (float*)a_kvp, (float*)a_ksp);
  kvred_kernel<<<dim3(64, 4), 256, 0, stream>>>(
      (float*)a_kvp, (float*)a_ksp, (unsigned short*)a_kvT, (float*)a_ksum);

  qkv_fused_kernel<<<dim3(32, 64), 256, 0, stream>>>(
      (unsigned short*)a_qb, (unsigned short*)a_pT, (unsigned short*)a_kvT,
      (float*)a_ksum, (unsigned short*)a_y);

  gemm_bt_kernel<1><<<dim3(128, 8, 1), 256, 0, stream>>>(
      (unsigned short*)a_y,
      (unsigned short*)a_WoT, nullptr, nullptr,
      bo, nullptr, nullptr, out, nullptr, nullptr);
}

// Round 14
// 335.834 us; speedup vs baseline: 1.3980x; 1.0160x over previous
//
#include <hip/hip_runtime.h>

// ---------- types & helpers ----------
typedef __attribute__((ext_vector_type(8))) short short8;
typedef __attribute__((ext_vector_type(4))) float f32x4;

#define MFMA16 __builtin_amdgcn_mfma_f32_16x16x32_bf16

#define GLOAD16(gp, lp) __builtin_amdgcn_global_load_lds(                      \
    (const __attribute__((address_space(1))) void*)(gp),                       \
    (__attribute__((address_space(3))) void*)(lp), 16, 0, 0)

__device__ __forceinline__ unsigned short f2bf(float f) {
  unsigned int u = __float_as_uint(f);
  unsigned int r = u + 0x7fffu + ((u >> 16) & 1u);
  return (unsigned short)(r >> 16);
}
__device__ __forceinline__ float bf2f(unsigned short h) {
  return __uint_as_float(((unsigned int)h) << 16);
}

// ---------- cast fp32 -> bf16 (vector4) ----------
__global__ __launch_bounds__(256) void cast_x_kernel(
    const float* __restrict__ in, unsigned short* __restrict__ out, int n4) {
  int i = blockIdx.x * 256 + threadIdx.x;
  if (i >= n4) return;
  float4 v = reinterpret_cast<const float4*>(in)[i];
  ushort4 o;
  o.x = f2bf(v.x); o.y = f2bf(v.y); o.z = f2bf(v.z); o.w = f2bf(v.w);
  reinterpret_cast<ushort4*>(out)[i] = o;
}

// ---------- transpose + cast fp32 -> bf16 : out[C][R] = in[R][C] ----------
__global__ __launch_bounds__(256) void tcast_f32_kernel(
    const float* __restrict__ in, unsigned short* __restrict__ out, int R, int C) {
  __shared__ float t[64][65];
  int c0 = blockIdx.x * 64, r0 = blockIdx.y * 64;
  int tx = threadIdx.x, ty = threadIdx.y;  // (64,4)
#pragma unroll
  for (int i = 0; i < 16; ++i)
    t[ty + 4 * i][tx] = in[(size_t)(r0 + ty + 4 * i) * C + c0 + tx];
  __syncthreads();
#pragma unroll
  for (int i = 0; i < 16; ++i)
    out[(size_t)(c0 + ty + 4 * i) * R + r0 + tx] = f2bf(t[tx][ty + 4 * i]);
}

// ---------- batched: transpose+cast the four 1024x1024 weight matrices ----------
__global__ __launch_bounds__(256) void tcast4_kernel(
    const float* __restrict__ i0, const float* __restrict__ i1,
    const float* __restrict__ i2, const float* __restrict__ i3,
    unsigned short* __restrict__ o0, unsigned short* __restrict__ o1,
    unsigned short* __restrict__ o2, unsigned short* __restrict__ o3) {
  const float* in = i0; unsigned short* out = o0;
  if (blockIdx.z == 1) { in = i1; out = o1; }
  else if (blockIdx.z == 2) { in = i2; out = o2; }
  else if (blockIdx.z == 3) { in = i3; out = o3; }
  __shared__ float t[64][65];
  int c0 = blockIdx.x * 64, r0 = blockIdx.y * 64;
  int tx = threadIdx.x, ty = threadIdx.y;  // (64,4)
#pragma unroll
  for (int i = 0; i < 16; ++i)
    t[ty + 4 * i][tx] = in[(size_t)(r0 + ty + 4 * i) * 1024 + c0 + tx];
  __syncthreads();
#pragma unroll
  for (int i = 0; i < 16; ++i)
    out[(size_t)(c0 + ty + 4 * i) * 1024 + r0 + tx] = f2bf(t[tx][ty + 4 * i]);
}

// ---------- big GEMM  C[M,1024] = A[M,1024] @ W (W stored [N][K]) ----------
// R8/R11 core (BK=32, VGPR~80, 3 blocks/CU) — measured local optimum.
// OUTF==1: fp32 out, grid (128,8,1).
// OUTF==3: grid (3072,1,1), z-interleaved XCD-aware decode; z==2 writes
// transposed vT via dynamic-LDS epilogue.
template <int OUTF>
__global__ __launch_bounds__(256) void gemm_bt_kernel(
    const unsigned short* __restrict__ A,
    const unsigned short* W0, const unsigned short* W1, const unsigned short* W2,
    const float* b0, const float* b1, const float* b2,
    void* o0, void* o1, void* o2) {
  constexpr int KD = 1024, ND = 1024;
  int m0, n0, z;
  if constexpr (OUTF == 3) {
    int id = blockIdx.x;
    int g = id / 24, slot = id - g * 24;
    z = slot >> 3;
    int t = g * 8 + (slot & 7);
    m0 = (t & 127) * 128;
    n0 = (t >> 7) * 128;
  } else {
    m0 = blockIdx.x * 128;
    n0 = blockIdx.y * 128;
    z = 0;
  }
  const unsigned short* W = W0; const float* bias = b0; void* op = o0;
  if (z == 1) { W = W1; bias = b1; op = o1; }
  else if (z == 2) { W = W2; bias = b2; op = o2; }

  __shared__ unsigned short lsA[128 * 32];
  __shared__ unsigned short lsB[128 * 32];
  extern __shared__ unsigned short tt[];  // allocated only for OUTF==3 launches
  int tid = threadIdx.x;
  int w = tid >> 6, lane = tid & 63;
  int lo = lane & 15, hi = lane >> 4;
  int wm = (w >> 1) * 64, wn = (w & 1) * 64;

  int srow0 = (w * 2 + 0) * 16 + (lane >> 2);
  int srow1 = (w * 2 + 1) * 16 + (lane >> 2);
  int scol = (lane & 3) * 8;
  const unsigned short* gA0 = A + (size_t)(m0 + srow0) * KD + scol;
  const unsigned short* gA1 = A + (size_t)(m0 + srow1) * KD + scol;
  const unsigned short* gB0 = W + (size_t)(n0 + srow0) * KD + scol;
  const unsigned short* gB1 = W + (size_t)(n0 + srow1) * KD + scol;
  unsigned short* lA0 = &lsA[(w * 2 + 0) * 512];
  unsigned short* lA1 = &lsA[(w * 2 + 1) * 512];
  unsigned short* lB0 = &lsB[(w * 2 + 0) * 512];
  unsigned short* lB1 = &lsB[(w * 2 + 1) * 512];

  f32x4 acc[4][4];
#pragma unroll
  for (int fm = 0; fm < 4; ++fm)
#pragma unroll
    for (int fn = 0; fn < 4; ++fn) acc[fm][fn] = (f32x4){0.f, 0.f, 0.f, 0.f};

  for (int kt = 0; kt < KD; kt += 32) {
    GLOAD16(gA0 + kt, lA0);
    GLOAD16(gA1 + kt, lA1);
    GLOAD16(gB0 + kt, lB0);
    GLOAD16(gB1 + kt, lB1);
    __syncthreads();
    short8 af[4], bfr[4];
#pragma unroll
    for (int fm = 0; fm < 4; ++fm)
      af[fm] = *reinterpret_cast<const short8*>(
          &lsA[(wm + fm * 16 + lo) * 32 + hi * 8]);
#pragma unroll
    for (int fn = 0; fn < 4; ++fn)
      bfr[fn] = *reinterpret_cast<const short8*>(
          &lsB[(wn + fn * 16 + lo) * 32 + hi * 8]);
#pragma unroll
    for (int fm = 0; fm < 4; ++fm)
#pragma unroll
      for (int fn = 0; fn < 4; ++fn)
        acc[fm][fn] = MFMA16(af[fm], bfr[fn], acc[fm][fn], 0, 0, 0);
    __syncthreads();
  }

  bool vpath = (OUTF == 3) && (z == 2);
#pragma unroll
  for (int fn = 0; fn < 4; ++fn) {
    int coll = wn + fn * 16 + lo;
    float bv = bias[n0 + coll];
#pragma unroll
    for (int fm = 0; fm < 4; ++fm) {
#pragma unroll
      for (int j = 0; j < 4; ++j) {
        int rowl = wm + fm * 16 + hi * 4 + j;
        float v = acc[fm][fn][j] + bv;
        if constexpr (OUTF == 1) {
          reinterpret_cast<float*>(op)[(size_t)(m0 + rowl) * ND + n0 + coll] = v;
        } else {
          if (vpath)
            tt[coll * 136 + rowl] = f2bf(v);
          else
            reinterpret_cast<unsigned short*>(op)[(size_t)(m0 + rowl) * ND + n0 + coll] =
                f2bf(v);
        }
      }
    }
  }
  if constexpr (OUTF == 3) {
    if (vpath) {
      __syncthreads();
      int b = m0 >> 12, tok0 = m0 & 4095;
      int c = tid >> 1, half = (tid & 1) * 64;
      unsigned short* dst = reinterpret_cast<unsigned short*>(op) +
                            (size_t)(b * 1024 + n0 + c) * 4096 + tok0 + half;
#pragma unroll
      for (int i = 0; i < 8; ++i) {
        short8 vv = *reinterpret_cast<const short8*>(&tt[c * 136 + half + i * 8]);
        *reinterpret_cast<short8*>(dst + i * 8) = vv;
      }
    }
  }
}

// ---------- fused featmap(k) + kv + ksum (split over N, S=8) ----------
// K: [16384][1024] bf16, PT: [256][64] bf16, VT: [(b*16+h)*64+d][4096] bf16
// kvp: [8][64 bh][256 f][64 d] fp32 parts, ksp: [8][64][256] fp32 parts
__global__ __launch_bounds__(256) void kv_fused_kernel(
    const unsigned short* __restrict__ K, const unsigned short* __restrict__ PT,
    const unsigned short* __restrict__ VT,
    float* __restrict__ kvp, float* __restrict__ ksp) {
  __shared__ unsigned short kp[256 * 40];  // [f][n] transposed k' tile, stride 40
  int s = blockIdx.x, bh = blockIdx.y, b = bh >> 4, h = bh & 15;
  int tid = threadIdx.x, w = tid >> 6, lane = tid & 63;
  int lo = lane & 15, hi = lane >> 4;
  int f0w = w * 64;

  short8 pb[4][2];
#pragma unroll
  for (int fn = 0; fn < 4; ++fn) {
    int f = f0w + fn * 16 + lo;
    pb[fn][0] = *reinterpret_cast<const short8*>(PT + (size_t)f * 64 + hi * 8);
    pb[fn][1] = *reinterpret_cast<const short8*>(PT + (size_t)f * 64 + 32 + hi * 8);
  }
  const unsigned short* vbase[4];
#pragma unroll
  for (int fn = 0; fn < 4; ++fn)
    vbase[fn] = VT + (size_t)(bh * 64 + fn * 16 + lo) * 4096;

  f32x4 acck[4][4];
#pragma unroll
  for (int fm = 0; fm < 4; ++fm)
#pragma unroll
    for (int fn = 0; fn < 4; ++fn) acck[fm][fn] = (f32x4){0.f, 0.f, 0.f, 0.f};
  float ks[4] = {0.f, 0.f, 0.f, 0.f};

  for (int c = 0; c < 16; ++c) {
    int n0 = s * 512 + c * 32;
    const unsigned short* Ab = K + (size_t)(b * 4096 + n0) * 1024 + h * 64;
    // issue ALL global loads up front (K chunk + V chunk are independent)
    short8 af[2][2], b2[4];
#pragma unroll
    for (int fm = 0; fm < 2; ++fm)
#pragma unroll
      for (int kt = 0; kt < 2; ++kt)
        af[fm][kt] = *reinterpret_cast<const short8*>(
            Ab + (size_t)(fm * 16 + lo) * 1024 + kt * 32 + hi * 8);
#pragma unroll
    for (int fn = 0; fn < 4; ++fn)
      b2[fn] = *reinterpret_cast<const short8*>(vbase[fn] + n0 + hi * 8);

    float dp[2] = {0.f, 0.f};
#pragma unroll
    for (int fm = 0; fm < 2; ++fm)
#pragma unroll
      for (int kt = 0; kt < 2; ++kt)
#pragma unroll
        for (int j = 0; j < 8; ++j) {
          float qv = bf2f((unsigned short)af[fm][kt][j]);
          dp[fm] += qv * qv;
        }
#pragma unroll
    for (int fm = 0; fm < 2; ++fm) {
      dp[fm] += __shfl_xor(dp[fm], 16);
      dp[fm] += __shfl_xor(dp[fm], 32);
    }
    // hoist: dg depends only on (fm, j) — 8 bpermutes instead of 32
    float dgv[2][4];
#pragma unroll
    for (int fm = 0; fm < 2; ++fm)
#pragma unroll
      for (int j = 0; j < 4; ++j) dgv[fm][j] = __shfl(dp[fm], hi * 4 + j);

    f32x4 accf[2][4];
#pragma unroll
    for (int fm = 0; fm < 2; ++fm)
#pragma unroll
      for (int fn = 0; fn < 4; ++fn) accf[fm][fn] = (f32x4){0.f, 0.f, 0.f, 0.f};
#pragma unroll
    for (int fn = 0; fn < 4; ++fn) {
      accf[0][fn] = MFMA16(af[0][0], pb[fn][0], accf[0][fn], 0, 0, 0);
      accf[0][fn] = MFMA16(af[0][1], pb[fn][1], accf[0][fn], 0, 0, 0);
      accf[1][fn] = MFMA16(af[1][0], pb[fn][0], accf[1][fn], 0, 0, 0);
      accf[1][fn] = MFMA16(af[1][1], pb[fn][1], accf[1][fn], 0, 0, 0);
    }
    // exp epilogue -> packed ushort4 LDS writes (wave-private stripe)
#pragma unroll
    for (int fm = 0; fm < 2; ++fm)
#pragma unroll
      for (int fn = 0; fn < 4; ++fn) {
        ushort4 pk;
#pragma unroll
        for (int j = 0; j < 4; ++j) {
          float v = 0.125f * (__expf(0.35355339059327373f * accf[fm][fn][j] -
                                     0.0625f * dgv[fm][j]) + 1e-6f);
          ks[fn] += v;
          ((unsigned short*)&pk)[j] = f2bf(v);
        }
        *reinterpret_cast<ushort4*>(&kp[(f0w + fn * 16 + lo) * 40 + fm * 16 + hi * 4]) = pk;
      }
    // kv MFMA: this wave's 64 f-rows x 64 d, K=32 (this chunk)
    short8 a2[4];
#pragma unroll
    for (int fm = 0; fm < 4; ++fm)
      a2[fm] = *reinterpret_cast<const short8*>(&kp[(f0w + fm * 16 + lo) * 40 + hi * 8]);
#pragma unroll
    for (int fm = 0; fm < 4; ++fm)
#pragma unroll
      for (int fn = 0; fn < 4; ++fn)
        acck[fm][fn] = MFMA16(a2[fm], b2[fn], acck[fm][fn], 0, 0, 0);
  }
#pragma unroll
  for (int fn = 0; fn < 4; ++fn) {
    float v = ks[fn];
    v += __shfl_xor(v, 16);
    v += __shfl_xor(v, 32);
    if (hi == 0)
      ksp[(size_t)(s * 64 + bh) * 256 + f0w + fn * 16 + lo] = v;
  }
#pragma unroll
  for (int fm = 0; fm < 4; ++fm)
#pragma unroll
    for (int fn = 0; fn < 4; ++fn)
#pragma unroll
      for (int j = 0; j < 4; ++j)
        kvp[((size_t)(s * 64 + bh) * 256 + f0w + fm * 16 + hi * 4 + j) * 64 + fn * 16 + lo] =
            acck[fm][fn][j];
}

// ---------- reduce parts -> kvT bf16 [bh][64 d][256 f], ksum fp32 [bh][256] ----------
__global__ __launch_bounds__(256) void kvred_kernel(
    const float* __restrict__ kvp, const float* __restrict__ ksp,
    unsigned short* __restrict__ kvT, float* __restrict__ ksum) {
  __shared__ float t[64][65];
  int bh = blockIdx.x, g = blockIdx.y, tid = threadIdx.x;
  int fbase = g * 64;
  int fo = tid >> 2, dq = (tid & 3) * 16;
  float sum[16];
#pragma unroll
  for (int i = 0; i < 16; ++i) sum[i] = 0.f;
#pragma unroll
  for (int s = 0; s < 8; ++s) {
    const float* base = kvp + ((size_t)(s * 64 + bh) * 256 + fbase + fo) * 64 + dq;
#pragma unroll
    for (int i = 0; i < 16; ++i) sum[i] += base[i];
  }
#pragma unroll
  for (int i = 0; i < 16; ++i) t[fo][dq + i] = sum[i];
  __syncthreads();
  int d = tid >> 2, fq = (tid & 3) * 16;
  unsigned short wv[16];
#pragma unroll
  for (int i = 0; i < 16; ++i) wv[i] = f2bf(t[fq + i][d]);
  unsigned short* dst = kvT + (size_t)(bh * 64 + d) * 256 + fbase + fq;
  *reinterpret_cast<short8*>(dst) = *reinterpret_cast<const short8*>(&wv[0]);
  *reinterpret_cast<short8*>(dst + 8) = *reinterpret_cast<const short8*>(&wv[8]);
  if (g == 0) {
    float tsum = 0.f;
#pragma unroll
    for (int s = 0; s < 8; ++s) tsum += ksp[(size_t)(s * 64 + bh) * 256 + tid];
    ksum[bh * 256 + tid] = tsum;
  }
}

// ---------- fused featmap(q) + qkv + norm (f split into two 128-halves) ----------
__global__ __launch_bounds__(256) void qkv_fused_kernel(
    const unsigned short* __restrict__ Q, const unsigned short* __restrict__ PT,
    const unsigned short* __restrict__ KVT, const float* __restrict__ KSUM,
    unsigned short* __restrict__ Y) {
  __shared__ unsigned short qp[128 * 128];  // XOR-swizzled q' half-tile (32KB)
  int bh = blockIdx.y, b = bh >> 4, h = bh & 15;
  int t0 = blockIdx.x * 128;
  int tid = threadIdx.x, w = tid >> 6, lane = tid & 63;
  int lo = lane & 15, hi = lane >> 4;
  int r0 = w * 32;
  const unsigned short* Ab = Q + (size_t)(b * 4096 + t0 + r0) * 1024 + h * 64;

  float ksr[16];
#pragma unroll
  for (int fn = 0; fn < 16; ++fn) ksr[fn] = KSUM[bh * 256 + fn * 16 + lo];

  short8 af[2][2];
  float dp[2] = {0.f, 0.f};
#pragma unroll
  for (int fm = 0; fm < 2; ++fm)
#pragma unroll
    for (int kt = 0; kt < 2; ++kt) {
      af[fm][kt] = *reinterpret_cast<const short8*>(
          Ab + (size_t)(fm * 16 + lo) * 1024 + kt * 32 + hi * 8);
#pragma unroll
      for (int j = 0; j < 8; ++j) {
        float qv = bf2f((unsigned short)af[fm][kt][j]);
        dp[fm] += qv * qv;
      }
    }
#pragma unroll
  for (int fm = 0; fm < 2; ++fm) {
    dp[fm] += __shfl_xor(dp[fm], 16);
    dp[fm] += __shfl_xor(dp[fm], 32);
  }
  // hoist: dg depends only on (fm, j) — 8 bpermutes instead of 128
  float dgv[2][4];
#pragma unroll
  for (int fm = 0; fm < 2; ++fm)
#pragma unroll
    for (int j = 0; j < 4; ++j) dgv[fm][j] = __shfl(dp[fm], hi * 4 + j);

  float np[2][4] = {{0.f, 0.f, 0.f, 0.f}, {0.f, 0.f, 0.f, 0.f}};
  f32x4 acco[2][4];
#pragma unroll
  for (int fm = 0; fm < 2; ++fm)
#pragma unroll
    for (int fn = 0; fn < 4; ++fn) acco[fm][fn] = (f32x4){0.f, 0.f, 0.f, 0.f};

#pragma unroll
  for (int hf = 0; hf < 2; ++hf) {
    f32x4 accf[2][8];
#pragma unroll
    for (int fm = 0; fm < 2; ++fm)
#pragma unroll
      for (int fn = 0; fn < 8; ++fn) accf[fm][fn] = (f32x4){0.f, 0.f, 0.f, 0.f};
#pragma unroll
    for (int fn = 0; fn < 8; ++fn) {
      int f = hf * 128 + fn * 16 + lo;
      short8 pb0 = *reinterpret_cast<const short8*>(PT + (size_t)f * 64 + hi * 8);
      short8 pb1 = *reinterpret_cast<const short8*>(PT + (size_t)f * 64 + 32 + hi * 8);
      accf[0][fn] = MFMA16(af[0][0], pb0, accf[0][fn], 0, 0, 0);
      accf[0][fn] = MFMA16(af[0][1], pb1, accf[0][fn], 0, 0, 0);
      accf[1][fn] = MFMA16(af[1][0], pb0, accf[1][fn], 0, 0, 0);
      accf[1][fn] = MFMA16(af[1][1], pb1, accf[1][fn], 0, 0, 0);
    }
#pragma unroll
    for (int fm = 0; fm < 2; ++fm)
#pragma unroll
      for (int fn = 0; fn < 8; ++fn)
#pragma unroll
        for (int j = 0; j < 4; ++j) {
          float v = 0.125f * (__expf(0.35355339059327373f * accf[fm][fn][j] -
                                     0.0625f * dgv[fm][j]) + 1e-6f);
          np[fm][j] += v * ksr[hf * 8 + fn];
          int row = r0 + fm * 16 + hi * 4 + j;
          int fl = fn * 16 + lo;
          int byt = (row * 256 + fl * 2) ^ ((row & 7) << 4);
          *reinterpret_cast<unsigned short*>(reinterpret_cast<char*>(qp) + byt) = f2bf(v);
        }
#pragma unroll
    for (int kt2 = 0; kt2 < 4; ++kt2) {
      short8 a2[2], b2[4];
#pragma unroll
      for (int fm = 0; fm < 2; ++fm) {
        int row = r0 + fm * 16 + lo;
        int byt = (row * 256 + kt2 * 64 + hi * 16) ^ ((row & 7) << 4);
        a2[fm] = *reinterpret_cast<const short8*>(reinterpret_cast<char*>(qp) + byt);
      }
#pragma unroll
      for (int fn = 0; fn < 4; ++fn)
        b2[fn] = *reinterpret_cast<const short8*>(
            KVT + (size_t)(bh * 64 + fn * 16 + lo) * 256 + hf * 128 + kt2 * 32 + hi * 8);
#pragma unroll
      for (int fm = 0; fm < 2; ++fm)
#pragma unroll
        for (int fn = 0; fn < 4; ++fn)
          acco[fm][fn] = MFMA16(a2[fm], b2[fn], acco[fm][fn], 0, 0, 0);
    }
  }
#pragma unroll
  for (int fm = 0; fm < 2; ++fm)
#pragma unroll
    for (int j = 0; j < 4; ++j) {
      np[fm][j] += __shfl_xor(np[fm][j], 1);
      np[fm][j] += __shfl_xor(np[fm][j], 2);
      np[fm][j] += __shfl_xor(np[fm][j], 4);
      np[fm][j] += __shfl_xor(np[fm][j], 8);
    }
#pragma unroll
  for (int fm = 0; fm < 2; ++fm)
#pragma unroll
    for (int j = 0; j < 4; ++j) {
      float nv = np[fm][j] + 1e-6f;
      int row = b * 4096 + t0 + r0 + fm * 16 + hi * 4 + j;
#pragma unroll
      for (int fn = 0; fn < 4; ++fn)
        Y[(size_t)row * 1024 + h * 64 + fn * 16 + lo] = f2bf(acco[fm][fn][j] / nv);
    }
}

// ---------- host ----------
extern "C" void kernel_launch(void* const* d_in, const int* in_sizes, int n_in,
                              void* d_out, int out_size, void* d_ws, size_t ws_size,
                              hipStream_t stream) {
  (void)in_sizes; (void)n_in; (void)out_size; (void)ws_size;
  const float* x    = (const float*)d_in[0];
  const float* Wq   = (const float*)d_in[2];
  const float* bq   = (const float*)d_in[3];
  const float* Wk   = (const float*)d_in[4];
  const float* bk   = (const float*)d_in[5];
  const float* Wv   = (const float*)d_in[6];
  const float* bv   = (const float*)d_in[7];
  const float* Wo   = (const float*)d_in[8];
  const float* bo   = (const float*)d_in[9];
  const float* proj = (const float*)d_in[10];
  float* out = (float*)d_out;

  constexpr size_t SZ_XB = (size_t)16384 * 1024 * 2;  // 32 MiB
  constexpr size_t SZ_W  = (size_t)1024 * 1024 * 2;   // 2 MiB
  constexpr size_t SZ_PT = (size_t)256 * 64 * 2;      // 32 KiB

  char* p = (char*)d_ws;
  size_t off = 0;
  char* a_xb  = p + off; off += SZ_XB;
  char* a_WqT = p + off; off += SZ_W;
  char* a_WkT = p + off; off += SZ_W;
  char* a_WvT = p + off; off += SZ_W;
  char* a_WoT = p + off; off += SZ_W;
  char* a_pT  = p + off; off += SZ_PT;
  char* a_qb  = p + off; off += SZ_XB;
  char* a_kb  = p + off; off += SZ_XB;
  char* a_ksp  = p + off; off += (size_t)8 * 64 * 256 * 4;       // 512 KiB
  char* a_kvT  = p + off; off += (size_t)64 * 64 * 256 * 2;      // 2 MiB
  char* a_ksum = p + off; off += (size_t)64 * 256 * 4;           // 64 KiB

  // Aliases (stream-order verified):
  // kvp parts (8 x 4 MiB = 32 MiB) alias xb — xb dead after the QKV GEMM.
  char* a_kvp = a_xb;
  // vT lives in d_out lower half; d_out fully overwritten by the final GEMM.
  char* a_vT = (char*)d_out;
  // y aliases kb (K data dead after kv_fused).
  char* a_y = a_kb;

  dim3 tb(64, 4);

  cast_x_kernel<<<16384, 256, 0, stream>>>(x, (unsigned short*)a_xb, 16384 * 1024 / 4);
  tcast4_kernel<<<dim3(16, 16, 4), tb, 0, stream>>>(
      Wq, Wk, Wv, Wo,
      (unsigned short*)a_WqT, (unsigned short*)a_WkT,
      (unsigned short*)a_WvT, (unsigned short*)a_WoT);
  tcast_f32_kernel<<<dim3(4, 1), tb, 0, stream>>>(proj, (unsigned short*)a_pT, 64, 256);

  // q, k, v in one z-interleaved launch; z==2 writes vT via LDS-transpose.
  gemm_bt_kernel<3><<<3072, 256, 128 * 136 * 2, stream>>>(
      (unsigned short*)a_xb,
      (unsigned short*)a_WqT, (unsigned short*)a_WkT, (unsigned short*)a_WvT,
      bq, bk, bv, a_qb, a_kb, a_vT);

  kv_fused_kernel<<<dim3(8, 64), 256, 0, stream>>>(
      (unsigned short*)a_kb, (unsigned short*)a_pT, (unsigned short*)a_vT,
      (float*)a_kvp, (float*)a_ksp);
  kvred_kernel<<<dim3(64, 4), 256, 0, stream>>>(
      (float*)a_kvp, (float*)a_ksp, (unsigned short*)a_kvT, (float*)a_ksum);

  qkv_fused_kernel<<<dim3(32, 64), 256, 0, stream>>>(
      (unsigned short*)a_qb, (unsigned short*)a_pT, (unsigned short*)a_kvT,
      (float*)a_ksum, (unsigned short*)a_y);

  gemm_bt_kernel<1><<<dim3(128, 8, 1), 256, 0, stream>>>(
      (unsigned short*)a_y,
      (unsigned short*)a_WoT, nullptr, nullptr,
      bo, nullptr, nullptr, out, nullptr, nullptr);
}

// Round 15
// 334.820 us; speedup vs baseline: 1.4022x; 1.0030x over previous
//
#include <hip/hip_runtime.h>

// ---------- types & helpers ----------
typedef __attribute__((ext_vector_type(8))) short short8;
typedef __attribute__((ext_vector_type(4))) float f32x4;

#define MFMA16 __builtin_amdgcn_mfma_f32_16x16x32_bf16

#define GLOAD16(gp, lp) __builtin_amdgcn_global_load_lds(                      \
    (const __attribute__((address_space(1))) void*)(gp),                       \
    (__attribute__((address_space(3))) void*)(lp), 16, 0, 0)

__device__ __forceinline__ unsigned short f2bf(float f) {
  unsigned int u = __float_as_uint(f);
  unsigned int r = u + 0x7fffu + ((u >> 16) & 1u);
  return (unsigned short)(r >> 16);
}
__device__ __forceinline__ float bf2f(unsigned short h) {
  return __uint_as_float(((unsigned int)h) << 16);
}

// ---------- cast fp32 -> bf16 (vector4) ----------
__global__ __launch_bounds__(256) void cast_x_kernel(
    const float* __restrict__ in, unsigned short* __restrict__ out, int n4) {
  int i = blockIdx.x * 256 + threadIdx.x;
  if (i >= n4) return;
  float4 v = reinterpret_cast<const float4*>(in)[i];
  ushort4 o;
  o.x = f2bf(v.x); o.y = f2bf(v.y); o.z = f2bf(v.z); o.w = f2bf(v.w);
  reinterpret_cast<ushort4*>(out)[i] = o;
}

// ---------- transpose + cast fp32 -> bf16 : out[C][R] = in[R][C] ----------
__global__ __launch_bounds__(256) void tcast_f32_kernel(
    const float* __restrict__ in, unsigned short* __restrict__ out, int R, int C) {
  __shared__ float t[64][65];
  int c0 = blockIdx.x * 64, r0 = blockIdx.y * 64;
  int tx = threadIdx.x, ty = threadIdx.y;  // (64,4)
#pragma unroll
  for (int i = 0; i < 16; ++i)
    t[ty + 4 * i][tx] = in[(size_t)(r0 + ty + 4 * i) * C + c0 + tx];
  __syncthreads();
#pragma unroll
  for (int i = 0; i < 16; ++i)
    out[(size_t)(c0 + ty + 4 * i) * R + r0 + tx] = f2bf(t[tx][ty + 4 * i]);
}

// ---------- batched: transpose+cast the four 1024x1024 weight matrices ----------
__global__ __launch_bounds__(256) void tcast4_kernel(
    const float* __restrict__ i0, const float* __restrict__ i1,
    const float* __restrict__ i2, const float* __restrict__ i3,
    unsigned short* __restrict__ o0, unsigned short* __restrict__ o1,
    unsigned short* __restrict__ o2, unsigned short* __restrict__ o3) {
  const float* in = i0; unsigned short* out = o0;
  if (blockIdx.z == 1) { in = i1; out = o1; }
  else if (blockIdx.z == 2) { in = i2; out = o2; }
  else if (blockIdx.z == 3) { in = i3; out = o3; }
  __shared__ float t[64][65];
  int c0 = blockIdx.x * 64, r0 = blockIdx.y * 64;
  int tx = threadIdx.x, ty = threadIdx.y;  // (64,4)
#pragma unroll
  for (int i = 0; i < 16; ++i)
    t[ty + 4 * i][tx] = in[(size_t)(r0 + ty + 4 * i) * 1024 + c0 + tx];
  __syncthreads();
#pragma unroll
  for (int i = 0; i < 16; ++i)
    out[(size_t)(c0 + ty + 4 * i) * 1024 + r0 + tx] = f2bf(t[tx][ty + 4 * i]);
}

// ---------- big GEMM  C[M,1024] = A[M,1024] @ W (W stored [N][K]) ----------
// R8/R11 core (BK=32, VGPR~80, 3 blocks/CU) + zero-cost XOR bank swizzle:
// LDS slot (row, cs) holds global 16B-chunk cs ^ ((row>>1)&3).
//  - staging: source chunk = (lane&3)^((lane>>3)&3) (lane-constant), LDS
//    dest linear (global_load_lds writes base+lane*16).
//  - reads: chunk = hi ^ ((lo>>1)&3) (lane-constant) -> per 32-lane half all
//    8 bank-groups active (was {0,1,4,5} only = 2x serialization).
// OUTF==1: fp32 out, grid (128,8,1).
// OUTF==3: grid (3072,1,1), z-interleaved XCD-aware decode; z==2 writes
// transposed vT via dynamic-LDS epilogue.
template <int OUTF>
__global__ __launch_bounds__(256) void gemm_bt_kernel(
    const unsigned short* __restrict__ A,
    const unsigned short* W0, const unsigned short* W1, const unsigned short* W2,
    const float* b0, const float* b1, const float* b2,
    void* o0, void* o1, void* o2) {
  constexpr int KD = 1024, ND = 1024;
  int m0, n0, z;
  if constexpr (OUTF == 3) {
    int id = blockIdx.x;
    int g = id / 24, slot = id - g * 24;
    z = slot >> 3;
    int t = g * 8 + (slot & 7);
    m0 = (t & 127) * 128;
    n0 = (t >> 7) * 128;
  } else {
    m0 = blockIdx.x * 128;
    n0 = blockIdx.y * 128;
    z = 0;
  }
  const unsigned short* W = W0; const float* bias = b0; void* op = o0;
  if (z == 1) { W = W1; bias = b1; op = o1; }
  else if (z == 2) { W = W2; bias = b2; op = o2; }

  __shared__ unsigned short lsA[128 * 32];
  __shared__ unsigned short lsB[128 * 32];
  extern __shared__ unsigned short tt[];  // allocated only for OUTF==3 launches
  int tid = threadIdx.x;
  int w = tid >> 6, lane = tid & 63;
  int lo = lane & 15, hi = lane >> 4;
  int wm = (w >> 1) * 64, wn = (w & 1) * 64;

  // staging: row = line*16 + (lane>>2); (row>>1)&3 = (lane>>3)&3.
  // source chunk = slot ^ (row>>1)&3 = (lane&3)^((lane>>3)&3)  (involution)
  int srow0 = (w * 2 + 0) * 16 + (lane >> 2);
  int srow1 = (w * 2 + 1) * 16 + (lane >> 2);
  int scol = ((lane & 3) ^ ((lane >> 3) & 3)) * 8;
  const unsigned short* gA0 = A + (size_t)(m0 + srow0) * KD + scol;
  const unsigned short* gA1 = A + (size_t)(m0 + srow1) * KD + scol;
  const unsigned short* gB0 = W + (size_t)(n0 + srow0) * KD + scol;
  const unsigned short* gB1 = W + (size_t)(n0 + srow1) * KD + scol;
  unsigned short* lA0 = &lsA[(w * 2 + 0) * 512];
  unsigned short* lA1 = &lsA[(w * 2 + 1) * 512];
  unsigned short* lB0 = &lsB[(w * 2 + 0) * 512];
  unsigned short* lB1 = &lsB[(w * 2 + 1) * 512];

  f32x4 acc[4][4];
#pragma unroll
  for (int fm = 0; fm < 4; ++fm)
#pragma unroll
    for (int fn = 0; fn < 4; ++fn) acc[fm][fn] = (f32x4){0.f, 0.f, 0.f, 0.f};

  // read-side chunk: fragment rows have (row>>1)&3 = (lo>>1)&3 (wm, f*16 are
  // multiples of 16); lane-constant offset, zero extra instructions.
  int rchunk = (hi ^ ((lo >> 1) & 3)) * 8;
  for (int kt = 0; kt < KD; kt += 32) {
    GLOAD16(gA0 + kt, lA0);
    GLOAD16(gA1 + kt, lA1);
    GLOAD16(gB0 + kt, lB0);
    GLOAD16(gB1 + kt, lB1);
    __syncthreads();
    short8 af[4], bfr[4];
#pragma unroll
    for (int fm = 0; fm < 4; ++fm)
      af[fm] = *reinterpret_cast<const short8*>(
          &lsA[(wm + fm * 16 + lo) * 32 + rchunk]);
#pragma unroll
    for (int fn = 0; fn < 4; ++fn)
      bfr[fn] = *reinterpret_cast<const short8*>(
          &lsB[(wn + fn * 16 + lo) * 32 + rchunk]);
#pragma unroll
    for (int fm = 0; fm < 4; ++fm)
#pragma unroll
      for (int fn = 0; fn < 4; ++fn)
        acc[fm][fn] = MFMA16(af[fm], bfr[fn], acc[fm][fn], 0, 0, 0);
    __syncthreads();
  }

  bool vpath = (OUTF == 3) && (z == 2);
#pragma unroll
  for (int fn = 0; fn < 4; ++fn) {
    int coll = wn + fn * 16 + lo;
    float bv = bias[n0 + coll];
#pragma unroll
    for (int fm = 0; fm < 4; ++fm) {
#pragma unroll
      for (int j = 0; j < 4; ++j) {
        int rowl = wm + fm * 16 + hi * 4 + j;
        float v = acc[fm][fn][j] + bv;
        if constexpr (OUTF == 1) {
          reinterpret_cast<float*>(op)[(size_t)(m0 + rowl) * ND + n0 + coll] = v;
        } else {
          if (vpath)
            tt[coll * 136 + rowl] = f2bf(v);
          else
            reinterpret_cast<unsigned short*>(op)[(size_t)(m0 + rowl) * ND + n0 + coll] =
                f2bf(v);
        }
      }
    }
  }
  if constexpr (OUTF == 3) {
    if (vpath) {
      __syncthreads();
      int b = m0 >> 12, tok0 = m0 & 4095;
      int c = tid >> 1, half = (tid & 1) * 64;
      unsigned short* dst = reinterpret_cast<unsigned short*>(op) +
                            (size_t)(b * 1024 + n0 + c) * 4096 + tok0 + half;
#pragma unroll
      for (int i = 0; i < 8; ++i) {
        short8 vv = *reinterpret_cast<const short8*>(&tt[c * 136 + half + i * 8]);
        *reinterpret_cast<short8*>(dst + i * 8) = vv;
      }
    }
  }
}

// ---------- fused featmap(k) + kv + ksum (split over N, S=8) ----------
// K: [16384][1024] bf16, PT: [256][64] bf16, VT: [(b*16+h)*64+d][4096] bf16
// kvp: [8][64 bh][256 f][64 d] fp32 parts, ksp: [8][64][256] fp32 parts
__global__ __launch_bounds__(256) void kv_fused_kernel(
    const unsigned short* __restrict__ K, const unsigned short* __restrict__ PT,
    const unsigned short* __restrict__ VT,
    float* __restrict__ kvp, float* __restrict__ ksp) {
  __shared__ unsigned short kp[256 * 40];  // [f][n] transposed k' tile, stride 40
  int s = blockIdx.x, bh = blockIdx.y, b = bh >> 4, h = bh & 15;
  int tid = threadIdx.x, w = tid >> 6, lane = tid & 63;
  int lo = lane & 15, hi = lane >> 4;
  int f0w = w * 64;

  short8 pb[4][2];
#pragma unroll
  for (int fn = 0; fn < 4; ++fn) {
    int f = f0w + fn * 16 + lo;
    pb[fn][0] = *reinterpret_cast<const short8*>(PT + (size_t)f * 64 + hi * 8);
    pb[fn][1] = *reinterpret_cast<const short8*>(PT + (size_t)f * 64 + 32 + hi * 8);
  }
  const unsigned short* vbase[4];
#pragma unroll
  for (int fn = 0; fn < 4; ++fn)
    vbase[fn] = VT + (size_t)(bh * 64 + fn * 16 + lo) * 4096;

  f32x4 acck[4][4];
#pragma unroll
  for (int fm = 0; fm < 4; ++fm)
#pragma unroll
    for (int fn = 0; fn < 4; ++fn) acck[fm][fn] = (f32x4){0.f, 0.f, 0.f, 0.f};
  float ks[4] = {0.f, 0.f, 0.f, 0.f};

  for (int c = 0; c < 16; ++c) {
    int n0 = s * 512 + c * 32;
    const unsigned short* Ab = K + (size_t)(b * 4096 + n0) * 1024 + h * 64;
    // issue ALL global loads up front (K chunk + V chunk are independent)
    short8 af[2][2], b2[4];
#pragma unroll
    for (int fm = 0; fm < 2; ++fm)
#pragma unroll
      for (int kt = 0; kt < 2; ++kt)
        af[fm][kt] = *reinterpret_cast<const short8*>(
            Ab + (size_t)(fm * 16 + lo) * 1024 + kt * 32 + hi * 8);
#pragma unroll
    for (int fn = 0; fn < 4; ++fn)
      b2[fn] = *reinterpret_cast<const short8*>(vbase[fn] + n0 + hi * 8);

    float dp[2] = {0.f, 0.f};
#pragma unroll
    for (int fm = 0; fm < 2; ++fm)
#pragma unroll
      for (int kt = 0; kt < 2; ++kt)
#pragma unroll
        for (int j = 0; j < 8; ++j) {
          float qv = bf2f((unsigned short)af[fm][kt][j]);
          dp[fm] += qv * qv;
        }
#pragma unroll
    for (int fm = 0; fm < 2; ++fm) {
      dp[fm] += __shfl_xor(dp[fm], 16);
      dp[fm] += __shfl_xor(dp[fm], 32);
    }
    // hoist: dg depends only on (fm, j) — 8 bpermutes instead of 32
    float dgv[2][4];
#pragma unroll
    for (int fm = 0; fm < 2; ++fm)
#pragma unroll
      for (int j = 0; j < 4; ++j) dgv[fm][j] = __shfl(dp[fm], hi * 4 + j);

    f32x4 accf[2][4];
#pragma unroll
    for (int fm = 0; fm < 2; ++fm)
#pragma unroll
      for (int fn = 0; fn < 4; ++fn) accf[fm][fn] = (f32x4){0.f, 0.f, 0.f, 0.f};
#pragma unroll
    for (int fn = 0; fn < 4; ++fn) {
      accf[0][fn] = MFMA16(af[0][0], pb[fn][0], accf[0][fn], 0, 0, 0);
      accf[0][fn] = MFMA16(af[0][1], pb[fn][1], accf[0][fn], 0, 0, 0);
      accf[1][fn] = MFMA16(af[1][0], pb[fn][0], accf[1][fn], 0, 0, 0);
      accf[1][fn] = MFMA16(af[1][1], pb[fn][1], accf[1][fn], 0, 0, 0);
    }
    // exp epilogue -> packed ushort4 LDS writes (wave-private stripe)
#pragma unroll
    for (int fm = 0; fm < 2; ++fm)
#pragma unroll
      for (int fn = 0; fn < 4; ++fn) {
        ushort4 pk;
#pragma unroll
        for (int j = 0; j < 4; ++j) {
          float v = 0.125f * (__expf(0.35355339059327373f * accf[fm][fn][j] -
                                     0.0625f * dgv[fm][j]) + 1e-6f);
          ks[fn] += v;
          ((unsigned short*)&pk)[j] = f2bf(v);
        }
        *reinterpret_cast<ushort4*>(&kp[(f0w + fn * 16 + lo) * 40 + fm * 16 + hi * 4]) = pk;
      }
    // kv MFMA: this wave's 64 f-rows x 64 d, K=32 (this chunk)
    short8 a2[4];
#pragma unroll
    for (int fm = 0; fm < 4; ++fm)
      a2[fm] = *reinterpret_cast<const short8*>(&kp[(f0w + fm * 16 + lo) * 40 + hi * 8]);
#pragma unroll
    for (int fm = 0; fm < 4; ++fm)
#pragma unroll
      for (int fn = 0; fn < 4; ++fn)
        acck[fm][fn] = MFMA16(a2[fm], b2[fn], acck[fm][fn], 0, 0, 0);
  }
#pragma unroll
  for (int fn = 0; fn < 4; ++fn) {
    float v = ks[fn];
    v += __shfl_xor(v, 16);
    v += __shfl_xor(v, 32);
    if (hi == 0)
      ksp[(size_t)(s * 64 + bh) * 256 + f0w + fn * 16 + lo] = v;
  }
#pragma unroll
  for (int fm = 0; fm < 4; ++fm)
#pragma unroll
    for (int fn = 0; fn < 4; ++fn)
#pragma unroll
      for (int j = 0; j < 4; ++j)
        kvp[((size_t)(s * 64 + bh) * 256 + f0w + fm * 16 + hi * 4 + j) * 64 + fn * 16 + lo] =
            acck[fm][fn][j];
}

// ---------- reduce parts -> kvT bf16 [bh][64 d][256 f], ksum fp32 [bh][256] ----------
__global__ __launch_bounds__(256) void kvred_kernel(
    const float* __restrict__ kvp, const float* __restrict__ ksp,
    unsigned short* __restrict__ kvT, float* __restrict__ ksum) {
  __shared__ float t[64][65];
  int bh = blockIdx.x, g = blockIdx.y, tid = threadIdx.x;
  int fbase = g * 64;
  int fo = tid >> 2, dq = (tid & 3) * 16;
  float sum[16];
#pragma unroll
  for (int i = 0; i < 16; ++i) sum[i] = 0.f;
#pragma unroll
  for (int s = 0; s < 8; ++s) {
    const float* base = kvp + ((size_t)(s * 64 + bh) * 256 + fbase + fo) * 64 + dq;
#pragma unroll
    for (int i = 0; i < 16; ++i) sum[i] += base[i];
  }
#pragma unroll
  for (int i = 0; i < 16; ++i) t[fo][dq + i] = sum[i];
  __syncthreads();
  int d = tid >> 2, fq = (tid & 3) * 16;
  unsigned short wv[16];
#pragma unroll
  for (int i = 0; i < 16; ++i) wv[i] = f2bf(t[fq + i][d]);
  unsigned short* dst = kvT + (size_t)(bh * 64 + d) * 256 + fbase + fq;
  *reinterpret_cast<short8*>(dst) = *reinterpret_cast<const short8*>(&wv[0]);
  *reinterpret_cast<short8*>(dst + 8) = *reinterpret_cast<const short8*>(&wv[8]);
  if (g == 0) {
    float tsum = 0.f;
#pragma unroll
    for (int s = 0; s < 8; ++s) tsum += ksp[(size_t)(s * 64 + bh) * 256 + tid];
    ksum[bh * 256 + tid] = tsum;
  }
}

// ---------- fused featmap(q) + qkv + norm (f split into two 128-halves) ----------
__global__ __launch_bounds__(256) void qkv_fused_kernel(
    const unsigned short* __restrict__ Q, const unsigned short* __restrict__ PT,
    const unsigned short* __restrict__ KVT, const float* __restrict__ KSUM,
    unsigned short* __restrict__ Y) {
  __shared__ unsigned short qp[128 * 128];  // XOR-swizzled q' half-tile (32KB)
  int bh = blockIdx.y, b = bh >> 4, h = bh & 15;
  int t0 = blockIdx.x * 128;
  int tid = threadIdx.x, w = tid >> 6, lane = tid & 63;
  int lo = lane & 15, hi = lane >> 4;
  int r0 = w * 32;
  const unsigned short* Ab = Q + (size_t)(b * 4096 + t0 + r0) * 1024 + h * 64;

  float ksr[16];
#pragma unroll
  for (int fn = 0; fn < 16; ++fn) ksr[fn] = KSUM[bh * 256 + fn * 16 + lo];

  short8 af[2][2];
  float dp[2] = {0.f, 0.f};
#pragma unroll
  for (int fm = 0; fm < 2; ++fm)
#pragma unroll
    for (int kt = 0; kt < 2; ++kt) {
      af[fm][kt] = *reinterpret_cast<const short8*>(
          Ab + (size_t)(fm * 16 + lo) * 1024 + kt * 32 + hi * 8);
#pragma unroll
      for (int j = 0; j < 8; ++j) {
        float qv = bf2f((unsigned short)af[fm][kt][j]);
        dp[fm] += qv * qv;
      }
    }
#pragma unroll
  for (int fm = 0; fm < 2; ++fm) {
    dp[fm] += __shfl_xor(dp[fm], 16);
    dp[fm] += __shfl_xor(dp[fm], 32);
  }
  // hoist: dg depends only on (fm, j) — 8 bpermutes instead of 128
  float dgv[2][4];
#pragma unroll
  for (int fm = 0; fm < 2; ++fm)
#pragma unroll
    for (int j = 0; j < 4; ++j) dgv[fm][j] = __shfl(dp[fm], hi * 4 + j);

  float np[2][4] = {{0.f, 0.f, 0.f, 0.f}, {0.f, 0.f, 0.f, 0.f}};
  f32x4 acco[2][4];
#pragma unroll
  for (int fm = 0; fm < 2; ++fm)
#pragma unroll
    for (int fn = 0; fn < 4; ++fn) acco[fm][fn] = (f32x4){0.f, 0.f, 0.f, 0.f};

#pragma unroll
  for (int hf = 0; hf < 2; ++hf) {
    f32x4 accf[2][8];
#pragma unroll
    for (int fm = 0; fm < 2; ++fm)
#pragma unroll
      for (int fn = 0; fn < 8; ++fn) accf[fm][fn] = (f32x4){0.f, 0.f, 0.f, 0.f};
#pragma unroll
    for (int fn = 0; fn < 8; ++fn) {
      int f = hf * 128 + fn * 16 + lo;
      short8 pb0 = *reinterpret_cast<const short8*>(PT + (size_t)f * 64 + hi * 8);
      short8 pb1 = *reinterpret_cast<const short8*>(PT + (size_t)f * 64 + 32 + hi * 8);
      accf[0][fn] = MFMA16(af[0][0], pb0, accf[0][fn], 0, 0, 0);
      accf[0][fn] = MFMA16(af[0][1], pb1, accf[0][fn], 0, 0, 0);
      accf[1][fn] = MFMA16(af[1][0], pb0, accf[1][fn], 0, 0, 0);
      accf[1][fn] = MFMA16(af[1][1], pb1, accf[1][fn], 0, 0, 0);
    }
#pragma unroll
    for (int fm = 0; fm < 2; ++fm)
#pragma unroll
      for (int fn = 0; fn < 8; ++fn)
#pragma unroll
        for (int j = 0; j < 4; ++j) {
          float v = 0.125f * (__expf(0.35355339059327373f * accf[fm][fn][j] -
                                     0.0625f * dgv[fm][j]) + 1e-6f);
          np[fm][j] += v * ksr[hf * 8 + fn];
          int row = r0 + fm * 16 + hi * 4 + j;
          int fl = fn * 16 + lo;
          int byt = (row * 256 + fl * 2) ^ ((row & 7) << 4);
          *reinterpret_cast<unsigned short*>(reinterpret_cast<char*>(qp) + byt) = f2bf(v);
        }
#pragma unroll
    for (int kt2 = 0; kt2 < 4; ++kt2) {
      short8 a2[2], b2[4];
#pragma unroll
      for (int fm = 0; fm < 2; ++fm) {
        int row = r0 + fm * 16 + lo;
        int byt = (row * 256 + kt2 * 64 + hi * 16) ^ ((row & 7) << 4);
        a2[fm] = *reinterpret_cast<const short8*>(reinterpret_cast<char*>(qp) + byt);
      }
#pragma unroll
      for (int fn = 0; fn < 4; ++fn)
        b2[fn] = *reinterpret_cast<const short8*>(
            KVT + (size_t)(bh * 64 + fn * 16 + lo) * 256 + hf * 128 + kt2 * 32 + hi * 8);
#pragma unroll
      for (int fm = 0; fm < 2; ++fm)
#pragma unroll
        for (int fn = 0; fn < 4; ++fn)
          acco[fm][fn] = MFMA16(a2[fm], b2[fn], acco[fm][fn], 0, 0, 0);
    }
  }
#pragma unroll
  for (int fm = 0; fm < 2; ++fm)
#pragma unroll
    for (int j = 0; j < 4; ++j) {
      np[fm][j] += __shfl_xor(np[fm][j], 1);
      np[fm][j] += __shfl_xor(np[fm][j], 2);
      np[fm][j] += __shfl_xor(np[fm][j], 4);
      np[fm][j] += __shfl_xor(np[fm][j], 8);
    }
#pragma unroll
  for (int fm = 0; fm < 2; ++fm)
#pragma unroll
    for (int j = 0; j < 4; ++j) {
      float nv = np[fm][j] + 1e-6f;
      int row = b * 4096 + t0 + r0 + fm * 16 + hi * 4 + j;
#pragma unroll
      for (int fn = 0; fn < 4; ++fn)
        Y[(size_t)row * 1024 + h * 64 + fn * 16 + lo] = f2bf(acco[fm][fn][j] / nv);
    }
}

// ---------- host ----------
extern "C" void kernel_launch(void* const* d_in, const int* in_sizes, int n_in,
                              void* d_out, int out_size, void* d_ws, size_t ws_size,
                              hipStream_t stream) {
  (void)in_sizes; (void)n_in; (void)out_size; (void)ws_size;
  const float* x    = (const float*)d_in[0];
  const float* Wq   = (const float*)d_in[2];
  const float* bq   = (const float*)d_in[3];
  const float* Wk   = (const float*)d_in[4];
  const float* bk   = (const float*)d_in[5];
  const float* Wv   = (const float*)d_in[6];
  const float* bv   = (const float*)d_in[7];
  const float* Wo   = (const float*)d_in[8];
  const float* bo   = (const float*)d_in[9];
  const float* proj = (const float*)d_in[10];
  float* out = (float*)d_out;

  constexpr size_t SZ_XB = (size_t)16384 * 1024 * 2;  // 32 MiB
  constexpr size_t SZ_W  = (size_t)1024 * 1024 * 2;   // 2 MiB
  constexpr size_t SZ_PT = (size_t)256 * 64 * 2;      // 32 KiB

  char* p = (char*)d_ws;
  size_t off = 0;
  char* a_xb  = p + off; off += SZ_XB;
  char* a_WqT = p + off; off += SZ_W;
  char* a_WkT = p + off; off += SZ_W;
  char* a_WvT = p + off; off += SZ_W;
  char* a_WoT = p + off; off += SZ_W;
  char* a_pT  = p + off; off += SZ_PT;
  char* a_qb  = p + off; off += SZ_XB;
  char* a_kb  = p + off; off += SZ_XB;
  char* a_ksp  = p + off; off += (size_t)8 * 64 * 256 * 4;       // 512 KiB
  char* a_kvT  = p + off; off += (size_t)64 * 64 * 256 * 2;      // 2 MiB
  char* a_ksum = p + off; off += (size_t)64 * 256 * 4;           // 64 KiB

  // Aliases (stream-order verified):
  // kvp parts (8 x 4 MiB = 32 MiB) alias xb — xb dead after the QKV GEMM.
  char* a_kvp = a_xb;
  // vT lives in d_out lower half; d_out fully overwritten by the final GEMM.
  char* a_vT = (char*)d_out;
  // y aliases kb (K data dead after kv_fused).
  char* a_y = a_kb;

  dim3 tb(64, 4);

  cast_x_kernel<<<16384, 256, 0, stream>>>(x, (unsigned short*)a_xb, 16384 * 1024 / 4);
  tcast4_kernel<<<dim3(16, 16, 4), tb, 0, stream>>>(
      Wq, Wk, Wv, Wo,
      (unsigned short*)a_WqT, (unsigned short*)a_WkT,
      (unsigned short*)a_WvT, (unsigned short*)a_WoT);
  tcast_f32_kernel<<<dim3(4, 1), tb, 0, stream>>>(proj, (unsigned short*)a_pT, 64, 256);

  // q, k, v in one z-interleaved launch; z==2 writes vT via LDS-transpose.
  gemm_bt_kernel<3><<<3072, 256, 128 * 136 * 2, stream>>>(
      (unsigned short*)a_xb,
      (unsigned short*)a_WqT, (unsigned short*)a_WkT, (unsigned short*)a_WvT,
      bq, bk, bv, a_qb, a_kb, a_vT);

  kv_fused_kernel<<<dim3(8, 64), 256, 0, stream>>>(
      (unsigned short*)a_kb, (unsigned short*)a_pT, (unsigned short*)a_vT,
      (float*)a_kvp, (float*)a_ksp);
  kvred_kernel<<<dim3(64, 4), 256, 0, stream>>>(
      (float*)a_kvp, (float*)a_ksp, (unsigned short*)a_kvT, (float*)a_ksum);

  qkv_fused_kernel<<<dim3(32, 64), 256, 0, stream>>>(
      (unsigned short*)a_qb, (unsigned short*)a_pT, (unsigned short*)a_kvT,
      (float*)a_ksum, (unsigned short*)a_y);

  gemm_bt_kernel<1><<<dim3(128, 8, 1), 256, 0, stream>>>(
      (unsigned short*)a_y,
      (unsigned short*)a_WoT, nullptr, nullptr,
      bo, nullptr, nullptr, out, nullptr, nullptr);
}